// Round 1
// baseline (1204.540 us; speedup 1.0000x reference)
//
#include <hip/hip_runtime.h>
#include <stdint.h>
#include <math.h>

#define NB 2
#define SS 2048
#define HH 2048
#define NHH 32
#define HDD 64
#define MM (NB*SS)   // 4096

typedef __attribute__((ext_vector_type(8))) short short8;
typedef __attribute__((ext_vector_type(4))) short short4v;
typedef __attribute__((ext_vector_type(4))) float f32x4;

static __device__ __forceinline__ short rne_bf16(float x) {
    uint32_t u = __builtin_bit_cast(uint32_t, x);
    u += 0x7FFFu + ((u >> 16) & 1u);
    return (short)(u >> 16);
}
static __device__ __forceinline__ float bf16f(short h) {
    return __builtin_bit_cast(float, (uint32_t)((uint16_t)h) << 16);
}

// ---------------- convert fp32 -> bf16 (plain) ----------------
__global__ void __launch_bounds__(256)
k_cvt(const float* __restrict__ in, short* __restrict__ out, int n4) {
    int i = blockIdx.x * blockDim.x + threadIdx.x;
    if (i >= n4) return;
    float4 f = reinterpret_cast<const float4*>(in)[i];
    short4v o;
    o.x = rne_bf16(f.x); o.y = rne_bf16(f.y);
    o.z = rne_bf16(f.z); o.w = rne_bf16(f.w);
    reinterpret_cast<short4v*>(out)[i] = o;
}

// ---------------- convert fp32 -> bf16 hi + lo (split) ----------------
__global__ void __launch_bounds__(256)
k_cvt_split(const float* __restrict__ in, short* __restrict__ hi, short* __restrict__ lo, int n4) {
    int i = blockIdx.x * blockDim.x + threadIdx.x;
    if (i >= n4) return;
    float4 f = reinterpret_cast<const float4*>(in)[i];
    short4v h, l;
    h.x = rne_bf16(f.x); l.x = rne_bf16(f.x - bf16f(h.x));
    h.y = rne_bf16(f.y); l.y = rne_bf16(f.y - bf16f(h.y));
    h.z = rne_bf16(f.z); l.z = rne_bf16(f.z - bf16f(h.z));
    h.w = rne_bf16(f.w); l.w = rne_bf16(f.w - bf16f(h.w));
    reinterpret_cast<short4v*>(hi)[i] = h;
    reinterpret_cast<short4v*>(lo)[i] = l;
}

// ---------------- QKV projection GEMM (bf16 MFMA) + RoPE epilogue ----------------
// C[M=4096][N=2048] = X @ W^T ; z=0->Q(rope), z=1->K(rope), z=2->V(transposed store)
__global__ void __launch_bounds__(256, 2)
k_gemm_qkv(const short* __restrict__ X,
           const short* __restrict__ Wqh, const short* __restrict__ Wkh, const short* __restrict__ Wvh,
           const float* __restrict__ cosT, const float* __restrict__ sinT,
           short* __restrict__ Qr, short* __restrict__ Kr, short* __restrict__ Vt)
{
    const int z = blockIdx.z;
    const short* W = (z == 0) ? Wqh : (z == 1) ? Wkh : Wvh;
    const int lane = threadIdx.x & 63;
    const int wave = threadIdx.x >> 6;
    const int lrow = lane & 15;
    const int quad = lane >> 4;
    const int m0 = blockIdx.y * 128 + (wave >> 1) * 64;
    const int n0 = blockIdx.x * 128 + (wave & 1) * 64;

    const short* Ap = X + (size_t)(m0 + lrow) * HH + quad * 8;
    const short* Bp = W + (size_t)(n0 + lrow) * HH + quad * 8;

    f32x4 acc[4][4];
    #pragma unroll
    for (int i = 0; i < 4; i++)
        #pragma unroll
        for (int j = 0; j < 4; j++) acc[i][j] = 0.f;

    #pragma unroll 1
    for (int k0 = 0; k0 < HH; k0 += 32) {
        short8 a[4], b[4];
        #pragma unroll
        for (int mt = 0; mt < 4; mt++)
            a[mt] = *reinterpret_cast<const short8*>(Ap + (size_t)mt * 16 * HH + k0);
        #pragma unroll
        for (int nt = 0; nt < 4; nt++)
            b[nt] = *reinterpret_cast<const short8*>(Bp + (size_t)nt * 16 * HH + k0);
        #pragma unroll
        for (int mt = 0; mt < 4; mt++)
            #pragma unroll
            for (int nt = 0; nt < 4; nt++)
                acc[mt][nt] = __builtin_amdgcn_mfma_f32_16x16x32_bf16(a[mt], b[nt], acc[mt][nt], 0, 0, 0);
    }

    // epilogue: C/D layout row = quad*4+r, col = lrow + 16*nt
    #pragma unroll
    for (int mt = 0; mt < 4; mt++) {
        #pragma unroll
        for (int r = 0; r < 4; r++) {
            int row = m0 + mt * 16 + quad * 4 + r;   // global m = b*S + s
            int b_i = row >> 11;
            int s_i = row & (SS - 1);
            #pragma unroll
            for (int nt = 0; nt < 4; nt++) {
                int col = n0 + nt * 16 + lrow;       // global n = h*64 + d
                int h_i = col >> 6;
                int d_i = col & 63;                  // = nt*16 + lrow (n0 % 64 == 0)
                float v = acc[mt][nt][r];
                if (z < 2) {
                    // rotate_half: d<32 -> -x[d+32] ; d>=32 -> x[d-32]; pair is nt^2 in same lane
                    float pair = (nt & 2) ? acc[mt][nt - 2][r] : -acc[mt][nt + 2][r];
                    float c = cosT[s_i * HDD + d_i];
                    float sn = sinT[s_i * HDD + d_i];
                    v = v * c + pair * sn;
                    short* dst = (z == 0) ? Qr : Kr;
                    dst[(((size_t)b_i * NHH + h_i) * SS + s_i) * HDD + d_i] = rne_bf16(v);
                } else {
                    Vt[(((size_t)b_i * NHH + h_i) * HDD + d_i) * SS + s_i] = rne_bf16(v);
                }
            }
        }
    }
}

// ---------------- flash attention (bf16 MFMA, fp32 online softmax, base 2) ----------------
// Qr/Kr: [B,NH,S,HD] bf16 ; Vt: [B,NH,HD,S] bf16 ; out: attn hi/lo bf16 [B*S][H]
__global__ void __launch_bounds__(256, 2)
k_attn(const short* __restrict__ Qr, const short* __restrict__ Kr, const short* __restrict__ Vt,
       const float* __restrict__ mask,
       short* __restrict__ Ah, short* __restrict__ Al)
{
    __shared__ float pl[4][16 * 68];   // per-wave 16x64 P tile, padded stride 68
    const int lane = threadIdx.x & 63;
    const int wave = threadIdx.x >> 6;
    const int lrow = lane & 15;
    const int quad = lane >> 4;
    const int b = blockIdx.z, h = blockIdx.y;
    const int q0 = blockIdx.x * 64 + wave * 16;

    const size_t bh = (size_t)b * NHH + h;
    const short* Qbase = Qr + (bh * SS + q0 + lrow) * HDD + quad * 8;
    short8 qf0 = *reinterpret_cast<const short8*>(Qbase);
    short8 qf1 = *reinterpret_cast<const short8*>(Qbase + 32);

    const short* Kbase = Kr + bh * SS * HDD;
    const short* Vbase = Vt + bh * (size_t)HDD * SS;
    const float* mrow = mask + b * SS;

    float m_run[4], l_run[4];
    f32x4 o[4];
    #pragma unroll
    for (int r = 0; r < 4; r++) { m_run[r] = -1e30f; l_run[r] = 0.f; }
    #pragma unroll
    for (int dt = 0; dt < 4; dt++) o[dt] = 0.f;

    float* plw = pl[wave];
    const float SCL = 0.18033688f;   // (1/sqrt(64)) * log2(e)
    const float L2E = 1.44269504f;

    #pragma unroll 1
    for (int k0 = 0; k0 < SS; k0 += 64) {
        f32x4 sacc[4];
        #pragma unroll
        for (int nt = 0; nt < 4; nt++) {
            const short* kp = Kbase + (size_t)(k0 + nt * 16 + lrow) * HDD + quad * 8;
            short8 kf0 = *reinterpret_cast<const short8*>(kp);
            short8 kf1 = *reinterpret_cast<const short8*>(kp + 32);
            f32x4 z4 = 0.f;
            z4 = __builtin_amdgcn_mfma_f32_16x16x32_bf16(qf0, kf0, z4, 0, 0, 0);
            sacc[nt] = __builtin_amdgcn_mfma_f32_16x16x32_bf16(qf1, kf1, z4, 0, 0, 0);
        }
        float mval[4];
        #pragma unroll
        for (int nt = 0; nt < 4; nt++) mval[nt] = mrow[k0 + nt * 16 + lrow] * L2E;

        float s2[4][4];
        #pragma unroll
        for (int nt = 0; nt < 4; nt++)
            #pragma unroll
            for (int r = 0; r < 4; r++)
                s2[nt][r] = sacc[nt][r] * SCL + mval[nt];

        float alpha[4];
        #pragma unroll
        for (int r = 0; r < 4; r++) {
            float v = fmaxf(fmaxf(s2[0][r], s2[1][r]), fmaxf(s2[2][r], s2[3][r]));
            v = fmaxf(v, __shfl_xor(v, 1, 64));
            v = fmaxf(v, __shfl_xor(v, 2, 64));
            v = fmaxf(v, __shfl_xor(v, 4, 64));
            v = fmaxf(v, __shfl_xor(v, 8, 64));
            float mn = fmaxf(m_run[r], v);
            alpha[r] = exp2f(m_run[r] - mn);
            m_run[r] = mn;
        }
        #pragma unroll
        for (int r = 0; r < 4; r++) {
            float s = 0.f;
            #pragma unroll
            for (int nt = 0; nt < 4; nt++) {
                float pv = exp2f(s2[nt][r] - m_run[r]);
                s2[nt][r] = pv;
                s += pv;
            }
            s += __shfl_xor(s, 1, 64);
            s += __shfl_xor(s, 2, 64);
            s += __shfl_xor(s, 4, 64);
            s += __shfl_xor(s, 8, 64);
            l_run[r] = alpha[r] * l_run[r] + s;
        }
        #pragma unroll
        for (int dt = 0; dt < 4; dt++)
            #pragma unroll
            for (int r = 0; r < 4; r++)
                o[dt][r] *= alpha[r];

        // P (C-layout) -> LDS -> A-layout bf16 frags
        #pragma unroll
        for (int nt = 0; nt < 4; nt++)
            #pragma unroll
            for (int r = 0; r < 4; r++)
                plw[(quad * 4 + r) * 68 + nt * 16 + lrow] = s2[nt][r];
        asm volatile("s_waitcnt lgkmcnt(0)" ::: "memory");
        short8 pf[2];
        #pragma unroll
        for (int s = 0; s < 2; s++) {
            const float* pp = plw + lrow * 68 + s * 32 + quad * 8;
            float4 x0 = *reinterpret_cast<const float4*>(pp);
            float4 x1 = *reinterpret_cast<const float4*>(pp + 4);
            short8 t;
            t[0] = rne_bf16(x0.x); t[1] = rne_bf16(x0.y); t[2] = rne_bf16(x0.z); t[3] = rne_bf16(x0.w);
            t[4] = rne_bf16(x1.x); t[5] = rne_bf16(x1.y); t[6] = rne_bf16(x1.z); t[7] = rne_bf16(x1.w);
            pf[s] = t;
        }
        #pragma unroll
        for (int dt = 0; dt < 4; dt++) {
            const short* vp = Vbase + (size_t)(dt * 16 + lrow) * SS + k0 + quad * 8;
            short8 vf0 = *reinterpret_cast<const short8*>(vp);
            short8 vf1 = *reinterpret_cast<const short8*>(vp + 32);
            o[dt] = __builtin_amdgcn_mfma_f32_16x16x32_bf16(pf[0], vf0, o[dt], 0, 0, 0);
            o[dt] = __builtin_amdgcn_mfma_f32_16x16x32_bf16(pf[1], vf1, o[dt], 0, 0, 0);
        }
    }

    // epilogue: normalize, split to hi/lo bf16, store [B*S][H]
    #pragma unroll
    for (int r = 0; r < 4; r++) {
        float inv = 1.f / l_run[r];
        int s_i = q0 + quad * 4 + r;
        size_t row = (size_t)b * SS + s_i;
        #pragma unroll
        for (int dt = 0; dt < 4; dt++) {
            float x = o[dt][r] * inv;
            short hi = rne_bf16(x);
            short lo = rne_bf16(x - bf16f(hi));
            size_t idx = row * HH + (size_t)h * 64 + dt * 16 + lrow;
            Ah[idx] = hi;
            Al[idx] = lo;
        }
    }
}

// ---------------- output projection GEMM, split-bf16 (3-term) ----------------
__global__ void __launch_bounds__(256, 2)
k_gemm_wo(const short* __restrict__ Ahh, const short* __restrict__ All,
          const short* __restrict__ Bh, const short* __restrict__ Bl,
          float* __restrict__ C)
{
    const int lane = threadIdx.x & 63;
    const int wave = threadIdx.x >> 6;
    const int lrow = lane & 15;
    const int quad = lane >> 4;
    const int m0 = blockIdx.y * 128 + (wave >> 1) * 64;
    const int n0 = blockIdx.x * 128 + (wave & 1) * 64;

    const short* Aph = Ahh + (size_t)(m0 + lrow) * HH + quad * 8;
    const short* Apl = All + (size_t)(m0 + lrow) * HH + quad * 8;
    const short* Bph = Bh + (size_t)(n0 + lrow) * HH + quad * 8;
    const short* Bpl = Bl + (size_t)(n0 + lrow) * HH + quad * 8;

    f32x4 acc[4][4];
    #pragma unroll
    for (int i = 0; i < 4; i++)
        #pragma unroll
        for (int j = 0; j < 4; j++) acc[i][j] = 0.f;

    #pragma unroll 1
    for (int k0 = 0; k0 < HH; k0 += 32) {
        short8 ah[4], al[4], bh[4], bl[4];
        #pragma unroll
        for (int mt = 0; mt < 4; mt++) {
            ah[mt] = *reinterpret_cast<const short8*>(Aph + (size_t)mt * 16 * HH + k0);
            al[mt] = *reinterpret_cast<const short8*>(Apl + (size_t)mt * 16 * HH + k0);
        }
        #pragma unroll
        for (int nt = 0; nt < 4; nt++) {
            bh[nt] = *reinterpret_cast<const short8*>(Bph + (size_t)nt * 16 * HH + k0);
            bl[nt] = *reinterpret_cast<const short8*>(Bpl + (size_t)nt * 16 * HH + k0);
        }
        #pragma unroll
        for (int mt = 0; mt < 4; mt++)
            #pragma unroll
            for (int nt = 0; nt < 4; nt++) {
                acc[mt][nt] = __builtin_amdgcn_mfma_f32_16x16x32_bf16(ah[mt], bh[nt], acc[mt][nt], 0, 0, 0);
                acc[mt][nt] = __builtin_amdgcn_mfma_f32_16x16x32_bf16(al[mt], bh[nt], acc[mt][nt], 0, 0, 0);
                acc[mt][nt] = __builtin_amdgcn_mfma_f32_16x16x32_bf16(ah[mt], bl[nt], acc[mt][nt], 0, 0, 0);
            }
    }

    #pragma unroll
    for (int mt = 0; mt < 4; mt++)
        #pragma unroll
        for (int r = 0; r < 4; r++) {
            int row = m0 + mt * 16 + quad * 4 + r;
            #pragma unroll
            for (int nt = 0; nt < 4; nt++) {
                int col = n0 + nt * 16 + lrow;
                C[(size_t)row * HH + col] = acc[mt][nt][r];
            }
        }
}

// ---------------- host launch ----------------
extern "C" void kernel_launch(void* const* d_in, const int* in_sizes, int n_in,
                              void* d_out, int out_size, void* d_ws, size_t ws_size,
                              hipStream_t stream) {
    const float* hidden = (const float*)d_in[0];
    const float* maskp  = (const float*)d_in[1];
    const float* cosT   = (const float*)d_in[2];
    const float* sinT   = (const float*)d_in[3];
    const float* Wq     = (const float*)d_in[4];
    const float* Wk     = (const float*)d_in[5];
    const float* Wv     = (const float*)d_in[6];
    const float* Wo     = (const float*)d_in[7];
    float* out = (float*)d_out;

    char* ws = (char*)d_ws;
    auto alloc = [&](size_t bytes) {
        char* p = ws;
        ws += (bytes + 255) & ~(size_t)255;
        return p;
    };
    const size_t XB = (size_t)MM * HH * sizeof(short);  // 16.78 MB
    const size_t WB = (size_t)HH * HH * sizeof(short);  //  8.39 MB
    short* Xh  = (short*)alloc(XB);
    short* Wqh = (short*)alloc(WB);
    short* Wkh = (short*)alloc(WB);
    short* Wvh = (short*)alloc(WB);
    short* Woh = (short*)alloc(WB);
    short* Wol = (short*)alloc(WB);
    short* Qr  = (short*)alloc(XB);
    short* Kr  = (short*)alloc(XB);
    short* Vt  = (short*)alloc(XB);
    short* Ah  = (short*)alloc(XB);
    short* Al  = (short*)alloc(XB);

    const int nX4 = MM * HH / 4;   // 2,097,152
    const int nW4 = HH * HH / 4;   // 1,048,576
    k_cvt<<<dim3(nX4 / 256), dim3(256), 0, stream>>>(hidden, Xh, nX4);
    k_cvt<<<dim3(nW4 / 256), dim3(256), 0, stream>>>(Wq, Wqh, nW4);
    k_cvt<<<dim3(nW4 / 256), dim3(256), 0, stream>>>(Wk, Wkh, nW4);
    k_cvt<<<dim3(nW4 / 256), dim3(256), 0, stream>>>(Wv, Wvh, nW4);
    k_cvt_split<<<dim3(nW4 / 256), dim3(256), 0, stream>>>(Wo, Woh, Wol, nW4);

    k_gemm_qkv<<<dim3(HH / 128, MM / 128, 3), dim3(256), 0, stream>>>(
        Xh, Wqh, Wkh, Wvh, cosT, sinT, Qr, Kr, Vt);

    k_attn<<<dim3(SS / 64, NHH, NB), dim3(256), 0, stream>>>(
        Qr, Kr, Vt, maskp, Ah, Al);

    k_gemm_wo<<<dim3(HH / 128, MM / 128), dim3(256), 0, stream>>>(
        Ah, Al, Woh, Wol, out);
}

// Round 2
// 899.000 us; speedup vs baseline: 1.3399x; 1.3399x over previous
//
#include <hip/hip_runtime.h>
#include <stdint.h>
#include <math.h>

#define NB 2
#define SS 2048
#define HH 2048
#define NHH 32
#define HDD 64
#define MM (NB*SS)   // 4096

typedef __attribute__((ext_vector_type(8))) short short8;
typedef __attribute__((ext_vector_type(4))) short short4v;
typedef __attribute__((ext_vector_type(4))) float f32x4;

static __device__ __forceinline__ short rne_bf16(float x) {
    uint32_t u = __builtin_bit_cast(uint32_t, x);
    u += 0x7FFFu + ((u >> 16) & 1u);
    return (short)(u >> 16);
}
static __device__ __forceinline__ float bf16f(short h) {
    return __builtin_bit_cast(float, (uint32_t)((uint16_t)h) << 16);
}
// pack two fp32 -> two bf16 (RNE) in one dword: low=bf16(a), high=bf16(b)
static __device__ __forceinline__ uint32_t pack_bf16_rne(float a, float b) {
    uint32_t ua = __builtin_bit_cast(uint32_t, a);
    uint32_t ub = __builtin_bit_cast(uint32_t, b);
    ua += 0x7FFFu + ((ua >> 16) & 1u);
    ub += 0x7FFFu + ((ub >> 16) & 1u);
    return __builtin_amdgcn_perm(ub, ua, 0x07060302);  // [ua.b2,ua.b3,ub.b2,ub.b3]
}
static __device__ __forceinline__ float fast_exp2(float x) {
    float r;
    asm("v_exp_f32 %0, %1" : "=v"(r) : "v"(x));
    return r;
}

// ---------------- convert fp32 -> bf16 (plain) ----------------
__global__ void __launch_bounds__(256)
k_cvt(const float* __restrict__ in, short* __restrict__ out, int n4) {
    int i = blockIdx.x * blockDim.x + threadIdx.x;
    if (i >= n4) return;
    float4 f = reinterpret_cast<const float4*>(in)[i];
    short4v o;
    o.x = rne_bf16(f.x); o.y = rne_bf16(f.y);
    o.z = rne_bf16(f.z); o.w = rne_bf16(f.w);
    reinterpret_cast<short4v*>(out)[i] = o;
}

// ---------------- convert fp32 -> bf16 hi + lo (split) ----------------
__global__ void __launch_bounds__(256)
k_cvt_split(const float* __restrict__ in, short* __restrict__ hi, short* __restrict__ lo, int n4) {
    int i = blockIdx.x * blockDim.x + threadIdx.x;
    if (i >= n4) return;
    float4 f = reinterpret_cast<const float4*>(in)[i];
    short4v h, l;
    h.x = rne_bf16(f.x); l.x = rne_bf16(f.x - bf16f(h.x));
    h.y = rne_bf16(f.y); l.y = rne_bf16(f.y - bf16f(h.y));
    h.z = rne_bf16(f.z); l.z = rne_bf16(f.z - bf16f(h.z));
    h.w = rne_bf16(f.w); l.w = rne_bf16(f.w - bf16f(h.w));
    reinterpret_cast<short4v*>(hi)[i] = h;
    reinterpret_cast<short4v*>(lo)[i] = l;
}

// ---------------- QKV projection GEMM (bf16 MFMA) + RoPE epilogue ----------------
// C[M=4096][N=2048] = X @ W^T ; z=0->Q(rope, pre-scaled by log2e/8), z=1->K(rope), z=2->V(transposed)
__global__ void __launch_bounds__(256, 2)
k_gemm_qkv(const short* __restrict__ X,
           const short* __restrict__ Wqh, const short* __restrict__ Wkh, const short* __restrict__ Wvh,
           const float* __restrict__ cosT, const float* __restrict__ sinT,
           short* __restrict__ Qr, short* __restrict__ Kr, short* __restrict__ Vt)
{
    const int z = blockIdx.z;
    const short* W = (z == 0) ? Wqh : (z == 1) ? Wkh : Wvh;
    const int lane = threadIdx.x & 63;
    const int wave = threadIdx.x >> 6;
    const int lrow = lane & 15;
    const int quad = lane >> 4;
    const int m0 = blockIdx.y * 128 + (wave >> 1) * 64;
    const int n0 = blockIdx.x * 128 + (wave & 1) * 64;

    const short* Ap = X + (size_t)(m0 + lrow) * HH + quad * 8;
    const short* Bp = W + (size_t)(n0 + lrow) * HH + quad * 8;

    f32x4 acc[4][4];
    #pragma unroll
    for (int i = 0; i < 4; i++)
        #pragma unroll
        for (int j = 0; j < 4; j++) acc[i][j] = 0.f;

    #pragma unroll 1
    for (int k0 = 0; k0 < HH; k0 += 32) {
        short8 a[4], b[4];
        #pragma unroll
        for (int mt = 0; mt < 4; mt++)
            a[mt] = *reinterpret_cast<const short8*>(Ap + (size_t)mt * 16 * HH + k0);
        #pragma unroll
        for (int nt = 0; nt < 4; nt++)
            b[nt] = *reinterpret_cast<const short8*>(Bp + (size_t)nt * 16 * HH + k0);
        #pragma unroll
        for (int mt = 0; mt < 4; mt++)
            #pragma unroll
            for (int nt = 0; nt < 4; nt++)
                acc[mt][nt] = __builtin_amdgcn_mfma_f32_16x16x32_bf16(a[mt], b[nt], acc[mt][nt], 0, 0, 0);
    }

    const float QSCL = 0.18033688011112042f;  // log2(e)/sqrt(HD)

    #pragma unroll
    for (int mt = 0; mt < 4; mt++) {
        #pragma unroll
        for (int r = 0; r < 4; r++) {
            int row = m0 + mt * 16 + quad * 4 + r;   // global m = b*S + s
            int b_i = row >> 11;
            int s_i = row & (SS - 1);
            #pragma unroll
            for (int nt = 0; nt < 4; nt++) {
                int col = n0 + nt * 16 + lrow;       // global n = h*64 + d
                int h_i = col >> 6;
                int d_i = col & 63;
                float v = acc[mt][nt][r];
                if (z < 2) {
                    float pair = (nt & 2) ? acc[mt][nt - 2][r] : -acc[mt][nt + 2][r];
                    float c = cosT[s_i * HDD + d_i];
                    float sn = sinT[s_i * HDD + d_i];
                    v = v * c + pair * sn;
                    if (z == 0) v *= QSCL;
                    short* dst = (z == 0) ? Qr : Kr;
                    dst[(((size_t)b_i * NHH + h_i) * SS + s_i) * HDD + d_i] = rne_bf16(v);
                } else {
                    Vt[(((size_t)b_i * NHH + h_i) * HDD + d_i) * SS + s_i] = rne_bf16(v);
                }
            }
        }
    }
}

// ---------------- flash attention v2: S^T MFMA + fixed-max softmax ----------------
// Qr (pre-scaled by log2e/8) / Kr: [B,NH,S,HD] bf16 ; Vt: [B,NH,HD,S] bf16
// out: attn hi/lo bf16 [B*S][H].
// Per wave: 64 q-rows. S^T = K@Q^T so softmax rows are in-lane (m = lane&15),
// keys are consecutive regs -> b64 packed-bf16 LDS writes, b128 A-frag reads.
// LDS P tile XOR-swizzled (16B granule ^ (m&7)): conflict-free both directions.
__global__ void __launch_bounds__(256, 2)
k_attn(const short* __restrict__ Qr, const short* __restrict__ Kr, const short* __restrict__ Vt,
       const float* __restrict__ mask,
       short* __restrict__ Ah, short* __restrict__ Al)
{
    __shared__ short plds[4][4096];   // per wave: 64 rows x 128 B (swizzled) = 8 KB
    const int lane = threadIdx.x & 63;
    const int wave = threadIdx.x >> 6;
    const int lrow = lane & 15;
    const int quad = lane >> 4;
    const int aofs = lrow & 7;
    const int b = blockIdx.z, h = blockIdx.y;
    const int q0w = blockIdx.x * 256 + wave * 64;

    const size_t bh = (size_t)b * NHH + h;
    const short* Qbase = Qr + bh * SS * HDD;
    const short* Kbase = Kr + bh * SS * HDD;
    const short* Vbase = Vt + bh * (size_t)HDD * SS;
    const float* mrow = mask + b * SS;
    char* cb = (char*)&plds[wave][0];

    // Q B-frags: B[m = nt*16+lrow][d = c*32+quad*8 ..]
    short8 qf[4][2];
    #pragma unroll
    for (int nt = 0; nt < 4; nt++)
        #pragma unroll
        for (int c = 0; c < 2; c++)
            qf[nt][c] = *reinterpret_cast<const short8*>(
                Qbase + (size_t)(q0w + nt * 16 + lrow) * HDD + c * 32 + quad * 8);

    f32x4 oacc[4][4];
    float l[4];
    #pragma unroll
    for (int i = 0; i < 4; i++) {
        l[i] = 0.f;
        #pragma unroll
        for (int j = 0; j < 4; j++) oacc[i][j] = 0.f;
    }

    const float L2E = 1.44269504f;

    #pragma unroll 1
    for (int k0 = 0; k0 < SS; k0 += 64) {
        // K A-frags: A[key = kt*16+lrow][d]
        short8 kf[4][2];
        #pragma unroll
        for (int kt = 0; kt < 4; kt++)
            #pragma unroll
            for (int c = 0; c < 2; c++)
                kf[kt][c] = *reinterpret_cast<const short8*>(
                    Kbase + (size_t)(k0 + kt * 16 + lrow) * HDD + c * 32 + quad * 8);

        // S^T tiles: rows=keys (quad*4+r), cols=m (lane&15)
        f32x4 sacc[4][4];
        #pragma unroll
        for (int kt = 0; kt < 4; kt++)
            #pragma unroll
            for (int nt = 0; nt < 4; nt++) {
                f32x4 z4 = 0.f;
                z4 = __builtin_amdgcn_mfma_f32_16x16x32_bf16(kf[kt][0], qf[nt][0], z4, 0, 0, 0);
                sacc[kt][nt] = __builtin_amdgcn_mfma_f32_16x16x32_bf16(kf[kt][1], qf[nt][1], z4, 0, 0, 0);
            }

        // drain previous iteration's P reads before overwriting (wave-private)
        asm volatile("s_waitcnt lgkmcnt(0)" ::: "memory");

        // softmax (fixed max): p = exp2(s + mask*log2e); keys in-lane
        #pragma unroll
        for (int kt = 0; kt < 4; kt++) {
            float4 mk = *reinterpret_cast<const float4*>(mrow + k0 + kt * 16 + quad * 4);
            float m0v = mk.x * L2E, m1v = mk.y * L2E, m2v = mk.z * L2E, m3v = mk.w * L2E;
            #pragma unroll
            for (int nt = 0; nt < 4; nt++) {
                float p0 = fast_exp2(sacc[kt][nt][0] + m0v);
                float p1 = fast_exp2(sacc[kt][nt][1] + m1v);
                float p2 = fast_exp2(sacc[kt][nt][2] + m2v);
                float p3 = fast_exp2(sacc[kt][nt][3] + m3v);
                l[nt] += (p0 + p1) + (p2 + p3);
                uint2 w;
                w.x = pack_bf16_rne(p0, p1);
                w.y = pack_bf16_rne(p2, p3);
                // P[m=nt*16+lrow][key=kt*16+quad*4 .. +3], swizzled
                *reinterpret_cast<uint2*>(
                    cb + (nt * 16 + lrow) * 128 +
                    (((2 * kt + (quad >> 1)) ^ aofs) * 16) + (quad & 1) * 8) = w;
            }
        }

        asm volatile("s_waitcnt lgkmcnt(0)" ::: "memory");

        // PV: A = P[m][key] from LDS, B = Vt[d][key]
        #pragma unroll
        for (int c = 0; c < 2; c++) {
            short8 pf[4], vf[4];
            #pragma unroll
            for (int mt = 0; mt < 4; mt++)
                pf[mt] = *reinterpret_cast<const short8*>(
                    cb + (mt * 16 + lrow) * 128 + (((4 * c + quad) ^ aofs) * 16));
            #pragma unroll
            for (int dt = 0; dt < 4; dt++)
                vf[dt] = *reinterpret_cast<const short8*>(
                    Vbase + (size_t)(dt * 16 + lrow) * SS + k0 + c * 32 + quad * 8);
            #pragma unroll
            for (int mt = 0; mt < 4; mt++)
                #pragma unroll
                for (int dt = 0; dt < 4; dt++)
                    oacc[mt][dt] = __builtin_amdgcn_mfma_f32_16x16x32_bf16(pf[mt], vf[dt], oacc[mt][dt], 0, 0, 0);
        }
    }

    // l: sum across quads (keys split over quads), then broadcast to C-layout rows
    #pragma unroll
    for (int nt = 0; nt < 4; nt++) {
        l[nt] += __shfl_xor(l[nt], 16, 64);
        l[nt] += __shfl_xor(l[nt], 32, 64);
    }
    float linv[4][4];
    #pragma unroll
    for (int mt = 0; mt < 4; mt++)
        #pragma unroll
        for (int r = 0; r < 4; r++)
            linv[mt][r] = 1.f / __shfl(l[mt], quad * 4 + r, 16);

    // epilogue: O C-layout row = mt*16+quad*4+r, col = dt*16+lrow
    #pragma unroll
    for (int mt = 0; mt < 4; mt++) {
        #pragma unroll
        for (int r = 0; r < 4; r++) {
            int s_i = q0w + mt * 16 + quad * 4 + r;
            size_t row = (size_t)b * SS + s_i;
            #pragma unroll
            for (int dt = 0; dt < 4; dt++) {
                float x = oacc[mt][dt][r] * linv[mt][r];
                short hi = rne_bf16(x);
                short lo = rne_bf16(x - bf16f(hi));
                size_t idx = row * HH + (size_t)h * 64 + dt * 16 + lrow;
                Ah[idx] = hi;
                Al[idx] = lo;
            }
        }
    }
}

// ---------------- output projection GEMM, split-bf16 (3-term) ----------------
__global__ void __launch_bounds__(256, 2)
k_gemm_wo(const short* __restrict__ Ahh, const short* __restrict__ All,
          const short* __restrict__ Bh, const short* __restrict__ Bl,
          float* __restrict__ C)
{
    const int lane = threadIdx.x & 63;
    const int wave = threadIdx.x >> 6;
    const int lrow = lane & 15;
    const int quad = lane >> 4;
    const int m0 = blockIdx.y * 128 + (wave >> 1) * 64;
    const int n0 = blockIdx.x * 128 + (wave & 1) * 64;

    const short* Aph = Ahh + (size_t)(m0 + lrow) * HH + quad * 8;
    const short* Apl = All + (size_t)(m0 + lrow) * HH + quad * 8;
    const short* Bph = Bh + (size_t)(n0 + lrow) * HH + quad * 8;
    const short* Bpl = Bl + (size_t)(n0 + lrow) * HH + quad * 8;

    f32x4 acc[4][4];
    #pragma unroll
    for (int i = 0; i < 4; i++)
        #pragma unroll
        for (int j = 0; j < 4; j++) acc[i][j] = 0.f;

    #pragma unroll 1
    for (int k0 = 0; k0 < HH; k0 += 32) {
        short8 ah[4], al[4], bh[4], bl[4];
        #pragma unroll
        for (int mt = 0; mt < 4; mt++) {
            ah[mt] = *reinterpret_cast<const short8*>(Aph + (size_t)mt * 16 * HH + k0);
            al[mt] = *reinterpret_cast<const short8*>(Apl + (size_t)mt * 16 * HH + k0);
        }
        #pragma unroll
        for (int nt = 0; nt < 4; nt++) {
            bh[nt] = *reinterpret_cast<const short8*>(Bph + (size_t)nt * 16 * HH + k0);
            bl[nt] = *reinterpret_cast<const short8*>(Bpl + (size_t)nt * 16 * HH + k0);
        }
        #pragma unroll
        for (int mt = 0; mt < 4; mt++)
            #pragma unroll
            for (int nt = 0; nt < 4; nt++) {
                acc[mt][nt] = __builtin_amdgcn_mfma_f32_16x16x32_bf16(ah[mt], bh[nt], acc[mt][nt], 0, 0, 0);
                acc[mt][nt] = __builtin_amdgcn_mfma_f32_16x16x32_bf16(al[mt], bh[nt], acc[mt][nt], 0, 0, 0);
                acc[mt][nt] = __builtin_amdgcn_mfma_f32_16x16x32_bf16(ah[mt], bl[nt], acc[mt][nt], 0, 0, 0);
            }
    }

    #pragma unroll
    for (int mt = 0; mt < 4; mt++)
        #pragma unroll
        for (int r = 0; r < 4; r++) {
            int row = m0 + mt * 16 + quad * 4 + r;
            #pragma unroll
            for (int nt = 0; nt < 4; nt++) {
                int col = n0 + nt * 16 + lrow;
                C[(size_t)row * HH + col] = acc[mt][nt][r];
            }
        }
}

// ---------------- host launch ----------------
extern "C" void kernel_launch(void* const* d_in, const int* in_sizes, int n_in,
                              void* d_out, int out_size, void* d_ws, size_t ws_size,
                              hipStream_t stream) {
    const float* hidden = (const float*)d_in[0];
    const float* maskp  = (const float*)d_in[1];
    const float* cosT   = (const float*)d_in[2];
    const float* sinT   = (const float*)d_in[3];
    const float* Wq     = (const float*)d_in[4];
    const float* Wk     = (const float*)d_in[5];
    const float* Wv     = (const float*)d_in[6];
    const float* Wo     = (const float*)d_in[7];
    float* out = (float*)d_out;

    char* ws = (char*)d_ws;
    auto alloc = [&](size_t bytes) {
        char* p = ws;
        ws += (bytes + 255) & ~(size_t)255;
        return p;
    };
    const size_t XB = (size_t)MM * HH * sizeof(short);  // 16.78 MB
    const size_t WB = (size_t)HH * HH * sizeof(short);  //  8.39 MB
    short* Xh  = (short*)alloc(XB);
    short* Wqh = (short*)alloc(WB);
    short* Wkh = (short*)alloc(WB);
    short* Wvh = (short*)alloc(WB);
    short* Woh = (short*)alloc(WB);
    short* Wol = (short*)alloc(WB);
    short* Qr  = (short*)alloc(XB);
    short* Kr  = (short*)alloc(XB);
    short* Vt  = (short*)alloc(XB);
    short* Ah  = (short*)alloc(XB);
    short* Al  = (short*)alloc(XB);

    const int nX4 = MM * HH / 4;
    const int nW4 = HH * HH / 4;
    k_cvt<<<dim3(nX4 / 256), dim3(256), 0, stream>>>(hidden, Xh, nX4);
    k_cvt<<<dim3(nW4 / 256), dim3(256), 0, stream>>>(Wq, Wqh, nW4);
    k_cvt<<<dim3(nW4 / 256), dim3(256), 0, stream>>>(Wk, Wkh, nW4);
    k_cvt<<<dim3(nW4 / 256), dim3(256), 0, stream>>>(Wv, Wvh, nW4);
    k_cvt_split<<<dim3(nW4 / 256), dim3(256), 0, stream>>>(Wo, Woh, Wol, nW4);

    k_gemm_qkv<<<dim3(HH / 128, MM / 128, 3), dim3(256), 0, stream>>>(
        Xh, Wqh, Wkh, Wvh, cosT, sinT, Qr, Kr, Vt);

    k_attn<<<dim3(SS / 256, NHH, NB), dim3(256), 0, stream>>>(
        Qr, Kr, Vt, maskp, Ah, Al);

    k_gemm_wo<<<dim3(HH / 128, MM / 128), dim3(256), 0, stream>>>(
        Ah, Al, Woh, Wol, out);
}

// Round 3
// 579.503 us; speedup vs baseline: 2.0786x; 1.5513x over previous
//
#include <hip/hip_runtime.h>
#include <stdint.h>
#include <math.h>

#define NB 2
#define SS 2048
#define HH 2048
#define NHH 32
#define HDD 64
#define MM (NB*SS)   // 4096

typedef __attribute__((ext_vector_type(8))) short short8;
typedef __attribute__((ext_vector_type(4))) short short4v;
typedef __attribute__((ext_vector_type(4))) float f32x4;

#define GLOBAL_AS const __attribute__((address_space(1))) void*
#define LDS_AS __attribute__((address_space(3))) void*

static __device__ __forceinline__ short rne_bf16(float x) {
    uint32_t u = __builtin_bit_cast(uint32_t, x);
    u += 0x7FFFu + ((u >> 16) & 1u);
    return (short)(u >> 16);
}
static __device__ __forceinline__ float bf16f(short h) {
    return __builtin_bit_cast(float, (uint32_t)((uint16_t)h) << 16);
}
static __device__ __forceinline__ uint32_t pack_bf16_rne(float a, float b) {
    uint32_t ua = __builtin_bit_cast(uint32_t, a);
    uint32_t ub = __builtin_bit_cast(uint32_t, b);
    ua += 0x7FFFu + ((ua >> 16) & 1u);
    ub += 0x7FFFu + ((ub >> 16) & 1u);
    return __builtin_amdgcn_perm(ub, ua, 0x07060302);
}
static __device__ __forceinline__ float fast_exp2(float x) {
    float r;
    asm("v_exp_f32 %0, %1" : "=v"(r) : "v"(x));
    return r;
}

// ---------------- convert fp32 -> bf16 (plain) ----------------
__global__ void __launch_bounds__(256)
k_cvt(const float* __restrict__ in, short* __restrict__ out, int n4) {
    int i = blockIdx.x * blockDim.x + threadIdx.x;
    if (i >= n4) return;
    float4 f = reinterpret_cast<const float4*>(in)[i];
    short4v o;
    o.x = rne_bf16(f.x); o.y = rne_bf16(f.y);
    o.z = rne_bf16(f.z); o.w = rne_bf16(f.w);
    reinterpret_cast<short4v*>(out)[i] = o;
}

// ---------------- convert fp32 -> bf16 hi + lo (split) ----------------
__global__ void __launch_bounds__(256)
k_cvt_split(const float* __restrict__ in, short* __restrict__ hi, short* __restrict__ lo, int n4) {
    int i = blockIdx.x * blockDim.x + threadIdx.x;
    if (i >= n4) return;
    float4 f = reinterpret_cast<const float4*>(in)[i];
    short4v h, l;
    h.x = rne_bf16(f.x); l.x = rne_bf16(f.x - bf16f(h.x));
    h.y = rne_bf16(f.y); l.y = rne_bf16(f.y - bf16f(h.y));
    h.z = rne_bf16(f.z); l.z = rne_bf16(f.z - bf16f(h.z));
    h.w = rne_bf16(f.w); l.w = rne_bf16(f.w - bf16f(h.w));
    reinterpret_cast<short4v*>(hi)[i] = h;
    reinterpret_cast<short4v*>(lo)[i] = l;
}

// ---------------- QKV projection GEMM (m97-style LDS staging) + RoPE ----------------
// C[4096][2048] = X @ W^T ; z=0->Q(rope, pre-scaled log2e/8), z=1->K(rope), z=2->V^T
// 128x128 block, BK=32; A/B tiles staged via global_load_lds width=16.
// LDS layout [row][k] stride 32 (NO padding: lane-contiguous requirement).
__global__ void __launch_bounds__(256, 2)
k_gemm_qkv(const short* __restrict__ X,
           const short* __restrict__ Wqh, const short* __restrict__ Wkh, const short* __restrict__ Wvh,
           const float* __restrict__ cosT, const float* __restrict__ sinT,
           short* __restrict__ Qr, short* __restrict__ Kr, short* __restrict__ Vt)
{
    __shared__ short lA[128 * 32];
    __shared__ short lB[128 * 32];
    const int z = blockIdx.z;
    const short* W = (z == 0) ? Wqh : (z == 1) ? Wkh : Wvh;
    const int tid = threadIdx.x;
    const int lane = tid & 63;
    const int wave = tid >> 6;
    const int lrow = lane & 15;
    const int quad = lane >> 4;
    const int mblk = blockIdx.y * 128;
    const int nblk = blockIdx.x * 128;
    const int m0 = mblk + (wave >> 1) * 64;
    const int n0 = nblk + (wave & 1) * 64;
    const int mw = (wave >> 1) * 64;
    const int nw = (wave & 1) * 64;

    // staging: wave w covers rows w*32 + j*16 + (lane>>2), k chunk (lane&3)*8
    const int srow = wave * 32 + (lane >> 2);
    const int skc = (lane & 3) * 8;
    const short* gA = X + (size_t)(mblk + srow) * HH + skc;
    const short* gB = W + (size_t)(nblk + srow) * HH + skc;
    short* lAw = &lA[wave * 1024];
    short* lBw = &lB[wave * 1024];

    f32x4 acc[4][4];
    #pragma unroll
    for (int i = 0; i < 4; i++)
        #pragma unroll
        for (int j = 0; j < 4; j++) acc[i][j] = 0.f;

    #pragma unroll 1
    for (int k0 = 0; k0 < HH; k0 += 32) {
        __syncthreads();
        #pragma unroll
        for (int j = 0; j < 2; j++) {
            __builtin_amdgcn_global_load_lds((GLOBAL_AS)(gA + (size_t)j * 16 * HH + k0),
                                             (LDS_AS)(lAw + j * 512), 16, 0, 0);
            __builtin_amdgcn_global_load_lds((GLOBAL_AS)(gB + (size_t)j * 16 * HH + k0),
                                             (LDS_AS)(lBw + j * 512), 16, 0, 0);
        }
        __syncthreads();

        short8 a[4], b[4];
        #pragma unroll
        for (int mt = 0; mt < 4; mt++)
            a[mt] = *reinterpret_cast<const short8*>(&lA[(mw + mt * 16 + lrow) * 32 + quad * 8]);
        #pragma unroll
        for (int nt = 0; nt < 4; nt++)
            b[nt] = *reinterpret_cast<const short8*>(&lB[(nw + nt * 16 + lrow) * 32 + quad * 8]);
        #pragma unroll
        for (int mt = 0; mt < 4; mt++)
            #pragma unroll
            for (int nt = 0; nt < 4; nt++)
                acc[mt][nt] = __builtin_amdgcn_mfma_f32_16x16x32_bf16(a[mt], b[nt], acc[mt][nt], 0, 0, 0);
    }

    const float QSCL = 0.18033688011112042f;  // log2(e)/sqrt(HD)

    #pragma unroll
    for (int mt = 0; mt < 4; mt++) {
        #pragma unroll
        for (int r = 0; r < 4; r++) {
            int row = m0 + mt * 16 + quad * 4 + r;   // global m = b*S + s
            int b_i = row >> 11;
            int s_i = row & (SS - 1);
            #pragma unroll
            for (int nt = 0; nt < 4; nt++) {
                int col = n0 + nt * 16 + lrow;       // global n = h*64 + d
                int h_i = col >> 6;
                int d_i = col & 63;
                float v = acc[mt][nt][r];
                if (z < 2) {
                    float pair = (nt & 2) ? acc[mt][nt - 2][r] : -acc[mt][nt + 2][r];
                    float c = cosT[s_i * HDD + d_i];
                    float sn = sinT[s_i * HDD + d_i];
                    v = v * c + pair * sn;
                    if (z == 0) v *= QSCL;
                    short* dst = (z == 0) ? Qr : Kr;
                    dst[(((size_t)b_i * NHH + h_i) * SS + s_i) * HDD + d_i] = rne_bf16(v);
                } else {
                    Vt[(((size_t)b_i * NHH + h_i) * HDD + d_i) * SS + s_i] = rne_bf16(v);
                }
            }
        }
    }
}

// ---------------- flash attention: S^T MFMA + fixed-max softmax ----------------
__global__ void __launch_bounds__(256, 2)
k_attn(const short* __restrict__ Qr, const short* __restrict__ Kr, const short* __restrict__ Vt,
       const float* __restrict__ mask,
       short* __restrict__ Ah, short* __restrict__ Al)
{
    __shared__ short plds[4][4096];   // per wave: 64 rows x 128 B (swizzled) = 8 KB
    const int lane = threadIdx.x & 63;
    const int wave = threadIdx.x >> 6;
    const int lrow = lane & 15;
    const int quad = lane >> 4;
    const int aofs = lrow & 7;
    const int b = blockIdx.z, h = blockIdx.y;
    const int q0w = blockIdx.x * 256 + wave * 64;

    const size_t bh = (size_t)b * NHH + h;
    const short* Qbase = Qr + bh * SS * HDD;
    const short* Kbase = Kr + bh * SS * HDD;
    const short* Vbase = Vt + bh * (size_t)HDD * SS;
    const float* mrow = mask + b * SS;
    char* cb = (char*)&plds[wave][0];

    short8 qf[4][2];
    #pragma unroll
    for (int nt = 0; nt < 4; nt++)
        #pragma unroll
        for (int c = 0; c < 2; c++)
            qf[nt][c] = *reinterpret_cast<const short8*>(
                Qbase + (size_t)(q0w + nt * 16 + lrow) * HDD + c * 32 + quad * 8);

    f32x4 oacc[4][4];
    float l[4];
    #pragma unroll
    for (int i = 0; i < 4; i++) {
        l[i] = 0.f;
        #pragma unroll
        for (int j = 0; j < 4; j++) oacc[i][j] = 0.f;
    }

    const float L2E = 1.44269504f;

    #pragma unroll 1
    for (int k0 = 0; k0 < SS; k0 += 64) {
        short8 kf[4][2];
        #pragma unroll
        for (int kt = 0; kt < 4; kt++)
            #pragma unroll
            for (int c = 0; c < 2; c++)
                kf[kt][c] = *reinterpret_cast<const short8*>(
                    Kbase + (size_t)(k0 + kt * 16 + lrow) * HDD + c * 32 + quad * 8);

        f32x4 sacc[4][4];
        #pragma unroll
        for (int kt = 0; kt < 4; kt++)
            #pragma unroll
            for (int nt = 0; nt < 4; nt++) {
                f32x4 z4 = 0.f;
                z4 = __builtin_amdgcn_mfma_f32_16x16x32_bf16(kf[kt][0], qf[nt][0], z4, 0, 0, 0);
                sacc[kt][nt] = __builtin_amdgcn_mfma_f32_16x16x32_bf16(kf[kt][1], qf[nt][1], z4, 0, 0, 0);
            }

        asm volatile("s_waitcnt lgkmcnt(0)" ::: "memory");

        #pragma unroll
        for (int kt = 0; kt < 4; kt++) {
            float4 mk = *reinterpret_cast<const float4*>(mrow + k0 + kt * 16 + quad * 4);
            float m0v = mk.x * L2E, m1v = mk.y * L2E, m2v = mk.z * L2E, m3v = mk.w * L2E;
            #pragma unroll
            for (int nt = 0; nt < 4; nt++) {
                float p0 = fast_exp2(sacc[kt][nt][0] + m0v);
                float p1 = fast_exp2(sacc[kt][nt][1] + m1v);
                float p2 = fast_exp2(sacc[kt][nt][2] + m2v);
                float p3 = fast_exp2(sacc[kt][nt][3] + m3v);
                l[nt] += (p0 + p1) + (p2 + p3);
                uint2 w;
                w.x = pack_bf16_rne(p0, p1);
                w.y = pack_bf16_rne(p2, p3);
                *reinterpret_cast<uint2*>(
                    cb + (nt * 16 + lrow) * 128 +
                    (((2 * kt + (quad >> 1)) ^ aofs) * 16) + (quad & 1) * 8) = w;
            }
        }

        asm volatile("s_waitcnt lgkmcnt(0)" ::: "memory");

        #pragma unroll
        for (int c = 0; c < 2; c++) {
            short8 pf[4], vf[4];
            #pragma unroll
            for (int mt = 0; mt < 4; mt++)
                pf[mt] = *reinterpret_cast<const short8*>(
                    cb + (mt * 16 + lrow) * 128 + (((4 * c + quad) ^ aofs) * 16));
            #pragma unroll
            for (int dt = 0; dt < 4; dt++)
                vf[dt] = *reinterpret_cast<const short8*>(
                    Vbase + (size_t)(dt * 16 + lrow) * SS + k0 + c * 32 + quad * 8);
            #pragma unroll
            for (int mt = 0; mt < 4; mt++)
                #pragma unroll
                for (int dt = 0; dt < 4; dt++)
                    oacc[mt][dt] = __builtin_amdgcn_mfma_f32_16x16x32_bf16(pf[mt], vf[dt], oacc[mt][dt], 0, 0, 0);
        }
    }

    #pragma unroll
    for (int nt = 0; nt < 4; nt++) {
        l[nt] += __shfl_xor(l[nt], 16, 64);
        l[nt] += __shfl_xor(l[nt], 32, 64);
    }
    float linv[4][4];
    #pragma unroll
    for (int mt = 0; mt < 4; mt++)
        #pragma unroll
        for (int r = 0; r < 4; r++)
            linv[mt][r] = 1.f / __shfl(l[mt], quad * 4 + r, 16);

    #pragma unroll
    for (int mt = 0; mt < 4; mt++) {
        #pragma unroll
        for (int r = 0; r < 4; r++) {
            int s_i = q0w + mt * 16 + quad * 4 + r;
            size_t row = (size_t)b * SS + s_i;
            #pragma unroll
            for (int dt = 0; dt < 4; dt++) {
                float x = oacc[mt][dt][r] * linv[mt][r];
                short hi = rne_bf16(x);
                short lo = rne_bf16(x - bf16f(hi));
                size_t idx = row * HH + (size_t)h * 64 + dt * 16 + lrow;
                Ah[idx] = hi;
                Al[idx] = lo;
            }
        }
    }
}

// ---------------- output projection GEMM, split-bf16 (3-term), LDS staged ----------------
__global__ void __launch_bounds__(256, 2)
k_gemm_wo(const short* __restrict__ Ahh, const short* __restrict__ All,
          const short* __restrict__ Bhh, const short* __restrict__ Bll,
          float* __restrict__ C)
{
    __shared__ short lAh[128 * 32];
    __shared__ short lAl[128 * 32];
    __shared__ short lBh[128 * 32];
    __shared__ short lBl[128 * 32];
    const int tid = threadIdx.x;
    const int lane = tid & 63;
    const int wave = tid >> 6;
    const int lrow = lane & 15;
    const int quad = lane >> 4;
    const int mblk = blockIdx.y * 128;
    const int nblk = blockIdx.x * 128;
    const int m0 = mblk + (wave >> 1) * 64;
    const int n0 = nblk + (wave & 1) * 64;
    const int mw = (wave >> 1) * 64;
    const int nw = (wave & 1) * 64;

    const int srow = wave * 32 + (lane >> 2);
    const int skc = (lane & 3) * 8;
    const short* gAh = Ahh + (size_t)(mblk + srow) * HH + skc;
    const short* gAl = All + (size_t)(mblk + srow) * HH + skc;
    const short* gBh = Bhh + (size_t)(nblk + srow) * HH + skc;
    const short* gBl = Bll + (size_t)(nblk + srow) * HH + skc;
    short* lAhw = &lAh[wave * 1024];
    short* lAlw = &lAl[wave * 1024];
    short* lBhw = &lBh[wave * 1024];
    short* lBlw = &lBl[wave * 1024];

    f32x4 acc[4][4];
    #pragma unroll
    for (int i = 0; i < 4; i++)
        #pragma unroll
        for (int j = 0; j < 4; j++) acc[i][j] = 0.f;

    #pragma unroll 1
    for (int k0 = 0; k0 < HH; k0 += 32) {
        __syncthreads();
        #pragma unroll
        for (int j = 0; j < 2; j++) {
            size_t go = (size_t)j * 16 * HH + k0;
            __builtin_amdgcn_global_load_lds((GLOBAL_AS)(gAh + go), (LDS_AS)(lAhw + j * 512), 16, 0, 0);
            __builtin_amdgcn_global_load_lds((GLOBAL_AS)(gAl + go), (LDS_AS)(lAlw + j * 512), 16, 0, 0);
            __builtin_amdgcn_global_load_lds((GLOBAL_AS)(gBh + go), (LDS_AS)(lBhw + j * 512), 16, 0, 0);
            __builtin_amdgcn_global_load_lds((GLOBAL_AS)(gBl + go), (LDS_AS)(lBlw + j * 512), 16, 0, 0);
        }
        __syncthreads();

        short8 ah[4], al[4], bh[4], bl[4];
        #pragma unroll
        for (int mt = 0; mt < 4; mt++) {
            int off = (mw + mt * 16 + lrow) * 32 + quad * 8;
            ah[mt] = *reinterpret_cast<const short8*>(&lAh[off]);
            al[mt] = *reinterpret_cast<const short8*>(&lAl[off]);
        }
        #pragma unroll
        for (int nt = 0; nt < 4; nt++) {
            int off = (nw + nt * 16 + lrow) * 32 + quad * 8;
            bh[nt] = *reinterpret_cast<const short8*>(&lBh[off]);
            bl[nt] = *reinterpret_cast<const short8*>(&lBl[off]);
        }
        #pragma unroll
        for (int mt = 0; mt < 4; mt++)
            #pragma unroll
            for (int nt = 0; nt < 4; nt++) {
                acc[mt][nt] = __builtin_amdgcn_mfma_f32_16x16x32_bf16(ah[mt], bh[nt], acc[mt][nt], 0, 0, 0);
                acc[mt][nt] = __builtin_amdgcn_mfma_f32_16x16x32_bf16(al[mt], bh[nt], acc[mt][nt], 0, 0, 0);
                acc[mt][nt] = __builtin_amdgcn_mfma_f32_16x16x32_bf16(ah[mt], bl[nt], acc[mt][nt], 0, 0, 0);
            }
    }

    #pragma unroll
    for (int mt = 0; mt < 4; mt++)
        #pragma unroll
        for (int r = 0; r < 4; r++) {
            int row = m0 + mt * 16 + quad * 4 + r;
            #pragma unroll
            for (int nt = 0; nt < 4; nt++) {
                int col = n0 + nt * 16 + lrow;
                C[(size_t)row * HH + col] = acc[mt][nt][r];
            }
        }
}

// ---------------- host launch ----------------
extern "C" void kernel_launch(void* const* d_in, const int* in_sizes, int n_in,
                              void* d_out, int out_size, void* d_ws, size_t ws_size,
                              hipStream_t stream) {
    const float* hidden = (const float*)d_in[0];
    const float* maskp  = (const float*)d_in[1];
    const float* cosT   = (const float*)d_in[2];
    const float* sinT   = (const float*)d_in[3];
    const float* Wq     = (const float*)d_in[4];
    const float* Wk     = (const float*)d_in[5];
    const float* Wv     = (const float*)d_in[6];
    const float* Wo     = (const float*)d_in[7];
    float* out = (float*)d_out;

    char* ws = (char*)d_ws;
    auto alloc = [&](size_t bytes) {
        char* p = ws;
        ws += (bytes + 255) & ~(size_t)255;
        return p;
    };
    const size_t XB = (size_t)MM * HH * sizeof(short);  // 16.78 MB
    const size_t WB = (size_t)HH * HH * sizeof(short);  //  8.39 MB
    short* Xh  = (short*)alloc(XB);
    short* Wqh = (short*)alloc(WB);
    short* Wkh = (short*)alloc(WB);
    short* Wvh = (short*)alloc(WB);
    short* Woh = (short*)alloc(WB);
    short* Wol = (short*)alloc(WB);
    short* Qr  = (short*)alloc(XB);
    short* Kr  = (short*)alloc(XB);
    short* Vt  = (short*)alloc(XB);
    short* Ah  = (short*)alloc(XB);
    short* Al  = (short*)alloc(XB);

    const int nX4 = MM * HH / 4;
    const int nW4 = HH * HH / 4;
    k_cvt<<<dim3(nX4 / 256), dim3(256), 0, stream>>>(hidden, Xh, nX4);
    k_cvt<<<dim3(nW4 / 256), dim3(256), 0, stream>>>(Wq, Wqh, nW4);
    k_cvt<<<dim3(nW4 / 256), dim3(256), 0, stream>>>(Wk, Wkh, nW4);
    k_cvt<<<dim3(nW4 / 256), dim3(256), 0, stream>>>(Wv, Wvh, nW4);
    k_cvt_split<<<dim3(nW4 / 256), dim3(256), 0, stream>>>(Wo, Woh, Wol, nW4);

    k_gemm_qkv<<<dim3(HH / 128, MM / 128, 3), dim3(256), 0, stream>>>(
        Xh, Wqh, Wkh, Wvh, cosT, sinT, Qr, Kr, Vt);

    k_attn<<<dim3(SS / 256, NHH, NB), dim3(256), 0, stream>>>(
        Qr, Kr, Vt, maskp, Ah, Al);

    k_gemm_wo<<<dim3(HH / 128, MM / 128), dim3(256), 0, stream>>>(
        Ah, Al, Woh, Wol, out);
}

// Round 4
// 511.141 us; speedup vs baseline: 2.3566x; 1.1337x over previous
//
#include <hip/hip_runtime.h>
#include <stdint.h>
#include <math.h>

#define NB 2
#define SS 2048
#define HH 2048
#define NHH 32
#define HDD 64
#define MM (NB*SS)   // 4096

typedef __attribute__((ext_vector_type(8))) short short8;
typedef __attribute__((ext_vector_type(4))) short short4v;
typedef __attribute__((ext_vector_type(4))) float f32x4;

#define GLOBAL_AS const __attribute__((address_space(1))) void*
#define LDS_AS __attribute__((address_space(3))) void*

static __device__ __forceinline__ short rne_bf16(float x) {
    uint32_t u = __builtin_bit_cast(uint32_t, x);
    u += 0x7FFFu + ((u >> 16) & 1u);
    return (short)(u >> 16);
}
static __device__ __forceinline__ float bf16f(short h) {
    return __builtin_bit_cast(float, (uint32_t)((uint16_t)h) << 16);
}
static __device__ __forceinline__ uint32_t pack_bf16_rne(float a, float b) {
    uint32_t ua = __builtin_bit_cast(uint32_t, a);
    uint32_t ub = __builtin_bit_cast(uint32_t, b);
    ua += 0x7FFFu + ((ua >> 16) & 1u);
    ub += 0x7FFFu + ((ub >> 16) & 1u);
    return __builtin_amdgcn_perm(ub, ua, 0x07060302);
}
static __device__ __forceinline__ float fast_exp2(float x) {
    float r;
    asm("v_exp_f32 %0, %1" : "=v"(r) : "v"(x));
    return r;
}

// ---------------- convert fp32 -> bf16 (plain) ----------------
__global__ void __launch_bounds__(256)
k_cvt(const float* __restrict__ in, short* __restrict__ out, int n4) {
    int i = blockIdx.x * blockDim.x + threadIdx.x;
    if (i >= n4) return;
    float4 f = reinterpret_cast<const float4*>(in)[i];
    short4v o;
    o.x = rne_bf16(f.x); o.y = rne_bf16(f.y);
    o.z = rne_bf16(f.z); o.w = rne_bf16(f.w);
    reinterpret_cast<short4v*>(out)[i] = o;
}

// ---------------- convert fp32 -> bf16 hi + lo (split) ----------------
__global__ void __launch_bounds__(256)
k_cvt_split(const float* __restrict__ in, short* __restrict__ hi, short* __restrict__ lo, int n4) {
    int i = blockIdx.x * blockDim.x + threadIdx.x;
    if (i >= n4) return;
    float4 f = reinterpret_cast<const float4*>(in)[i];
    short4v h, l;
    h.x = rne_bf16(f.x); l.x = rne_bf16(f.x - bf16f(h.x));
    h.y = rne_bf16(f.y); l.y = rne_bf16(f.y - bf16f(h.y));
    h.z = rne_bf16(f.z); l.z = rne_bf16(f.z - bf16f(h.z));
    h.w = rne_bf16(f.w); l.w = rne_bf16(f.w - bf16f(h.w));
    reinterpret_cast<short4v*>(hi)[i] = h;
    reinterpret_cast<short4v*>(lo)[i] = l;
}

// ---------------- fused QKV projection GEMM + RoPE ----------------
// One block computes 128x128 tiles of Q, K, V simultaneously, sharing the
// A (X) tile: per K-step stage 4 tiles (A,Bq,Bk,Bv) and run 48 MFMAs.
__global__ void __launch_bounds__(256, 2)
k_gemm_qkv(const short* __restrict__ X,
           const short* __restrict__ Wqh, const short* __restrict__ Wkh, const short* __restrict__ Wvh,
           const float* __restrict__ cosT, const float* __restrict__ sinT,
           short* __restrict__ Qr, short* __restrict__ Kr, short* __restrict__ Vt)
{
    __shared__ short lA[128 * 32];
    __shared__ short lBq[128 * 32];
    __shared__ short lBk[128 * 32];
    __shared__ short lBv[128 * 32];
    const int tid = threadIdx.x;
    const int lane = tid & 63;
    const int wave = tid >> 6;
    const int lrow = lane & 15;
    const int quad = lane >> 4;
    const int mblk = blockIdx.y * 128;
    const int nblk = blockIdx.x * 128;
    const int m0 = mblk + (wave >> 1) * 64;
    const int n0 = nblk + (wave & 1) * 64;
    const int mw = (wave >> 1) * 64;
    const int nw = (wave & 1) * 64;

    // staging: wave w covers rows w*32 + j*16 + (lane>>2), k chunk (lane&3)*8
    const int srow = wave * 32 + (lane >> 2);
    const int skc = (lane & 3) * 8;
    const short* gA = X   + (size_t)(mblk + srow) * HH + skc;
    const short* gQ = Wqh + (size_t)(nblk + srow) * HH + skc;
    const short* gK = Wkh + (size_t)(nblk + srow) * HH + skc;
    const short* gV = Wvh + (size_t)(nblk + srow) * HH + skc;
    const int lofs = wave * 1024;

    f32x4 acc[3][4][4];
    #pragma unroll
    for (int z = 0; z < 3; z++)
        #pragma unroll
        for (int i = 0; i < 4; i++)
            #pragma unroll
            for (int j = 0; j < 4; j++) acc[z][i][j] = 0.f;

    #pragma unroll 1
    for (int k0 = 0; k0 < HH; k0 += 32) {
        __syncthreads();
        #pragma unroll
        for (int j = 0; j < 2; j++) {
            size_t go = (size_t)j * 16 * HH + k0;
            int lo = lofs + j * 512;
            __builtin_amdgcn_global_load_lds((GLOBAL_AS)(gA + go), (LDS_AS)(&lA[lo]),  16, 0, 0);
            __builtin_amdgcn_global_load_lds((GLOBAL_AS)(gQ + go), (LDS_AS)(&lBq[lo]), 16, 0, 0);
            __builtin_amdgcn_global_load_lds((GLOBAL_AS)(gK + go), (LDS_AS)(&lBk[lo]), 16, 0, 0);
            __builtin_amdgcn_global_load_lds((GLOBAL_AS)(gV + go), (LDS_AS)(&lBv[lo]), 16, 0, 0);
        }
        __syncthreads();

        short8 a[4];
        #pragma unroll
        for (int mt = 0; mt < 4; mt++)
            a[mt] = *reinterpret_cast<const short8*>(&lA[(mw + mt * 16 + lrow) * 32 + quad * 8]);

        const short* lBz[3] = { lBq, lBk, lBv };
        #pragma unroll
        for (int z = 0; z < 3; z++) {
            short8 b[4];
            #pragma unroll
            for (int nt = 0; nt < 4; nt++)
                b[nt] = *reinterpret_cast<const short8*>(&lBz[z][(nw + nt * 16 + lrow) * 32 + quad * 8]);
            #pragma unroll
            for (int mt = 0; mt < 4; mt++)
                #pragma unroll
                for (int nt = 0; nt < 4; nt++)
                    acc[z][mt][nt] = __builtin_amdgcn_mfma_f32_16x16x32_bf16(a[mt], b[nt], acc[z][mt][nt], 0, 0, 0);
        }
    }

    const float QSCL = 0.18033688011112042f;  // log2(e)/sqrt(HD)

    #pragma unroll
    for (int z = 0; z < 3; z++) {
        #pragma unroll
        for (int mt = 0; mt < 4; mt++) {
            #pragma unroll
            for (int r = 0; r < 4; r++) {
                int row = m0 + mt * 16 + quad * 4 + r;   // global m = b*S + s
                int b_i = row >> 11;
                int s_i = row & (SS - 1);
                #pragma unroll
                for (int nt = 0; nt < 4; nt++) {
                    int col = n0 + nt * 16 + lrow;       // global n = h*64 + d
                    int h_i = col >> 6;
                    int d_i = col & 63;
                    float v = acc[z][mt][nt][r];
                    if (z < 2) {
                        float pair = (nt & 2) ? acc[z][mt][nt - 2][r] : -acc[z][mt][nt + 2][r];
                        float c = cosT[s_i * HDD + d_i];
                        float sn = sinT[s_i * HDD + d_i];
                        v = v * c + pair * sn;
                        if (z == 0) v *= QSCL;
                        short* dst = (z == 0) ? Qr : Kr;
                        dst[(((size_t)b_i * NHH + h_i) * SS + s_i) * HDD + d_i] = rne_bf16(v);
                    } else {
                        Vt[(((size_t)b_i * NHH + h_i) * HDD + d_i) * SS + s_i] = rne_bf16(v);
                    }
                }
            }
        }
    }
}

// ---------------- flash attention: S^T MFMA + fixed-max softmax ----------------
__global__ void __launch_bounds__(256, 2)
k_attn(const short* __restrict__ Qr, const short* __restrict__ Kr, const short* __restrict__ Vt,
       const float* __restrict__ mask,
       short* __restrict__ Ah, short* __restrict__ Al)
{
    __shared__ short plds[4][4096];   // per wave: 64 rows x 128 B (swizzled) = 8 KB
    const int lane = threadIdx.x & 63;
    const int wave = threadIdx.x >> 6;
    const int lrow = lane & 15;
    const int quad = lane >> 4;
    const int aofs = lrow & 7;
    const int b = blockIdx.z, h = blockIdx.y;
    const int q0w = blockIdx.x * 256 + wave * 64;

    const size_t bh = (size_t)b * NHH + h;
    const short* Qbase = Qr + bh * SS * HDD;
    const short* Kbase = Kr + bh * SS * HDD;
    const short* Vbase = Vt + bh * (size_t)HDD * SS;
    const float* mrow = mask + b * SS;
    char* cb = (char*)&plds[wave][0];

    short8 qf[4][2];
    #pragma unroll
    for (int nt = 0; nt < 4; nt++)
        #pragma unroll
        for (int c = 0; c < 2; c++)
            qf[nt][c] = *reinterpret_cast<const short8*>(
                Qbase + (size_t)(q0w + nt * 16 + lrow) * HDD + c * 32 + quad * 8);

    f32x4 oacc[4][4];
    float l[4];
    #pragma unroll
    for (int i = 0; i < 4; i++) {
        l[i] = 0.f;
        #pragma unroll
        for (int j = 0; j < 4; j++) oacc[i][j] = 0.f;
    }

    const float L2E = 1.44269504f;

    #pragma unroll 1
    for (int k0 = 0; k0 < SS; k0 += 64) {
        short8 kf[4][2];
        #pragma unroll
        for (int kt = 0; kt < 4; kt++)
            #pragma unroll
            for (int c = 0; c < 2; c++)
                kf[kt][c] = *reinterpret_cast<const short8*>(
                    Kbase + (size_t)(k0 + kt * 16 + lrow) * HDD + c * 32 + quad * 8);

        f32x4 sacc[4][4];
        #pragma unroll
        for (int kt = 0; kt < 4; kt++)
            #pragma unroll
            for (int nt = 0; nt < 4; nt++) {
                f32x4 z4 = 0.f;
                z4 = __builtin_amdgcn_mfma_f32_16x16x32_bf16(kf[kt][0], qf[nt][0], z4, 0, 0, 0);
                sacc[kt][nt] = __builtin_amdgcn_mfma_f32_16x16x32_bf16(kf[kt][1], qf[nt][1], z4, 0, 0, 0);
            }

        asm volatile("s_waitcnt lgkmcnt(0)" ::: "memory");

        #pragma unroll
        for (int kt = 0; kt < 4; kt++) {
            float4 mk = *reinterpret_cast<const float4*>(mrow + k0 + kt * 16 + quad * 4);
            float m0v = mk.x * L2E, m1v = mk.y * L2E, m2v = mk.z * L2E, m3v = mk.w * L2E;
            #pragma unroll
            for (int nt = 0; nt < 4; nt++) {
                float p0 = fast_exp2(sacc[kt][nt][0] + m0v);
                float p1 = fast_exp2(sacc[kt][nt][1] + m1v);
                float p2 = fast_exp2(sacc[kt][nt][2] + m2v);
                float p3 = fast_exp2(sacc[kt][nt][3] + m3v);
                l[nt] += (p0 + p1) + (p2 + p3);
                uint2 w;
                w.x = pack_bf16_rne(p0, p1);
                w.y = pack_bf16_rne(p2, p3);
                *reinterpret_cast<uint2*>(
                    cb + (nt * 16 + lrow) * 128 +
                    (((2 * kt + (quad >> 1)) ^ aofs) * 16) + (quad & 1) * 8) = w;
            }
        }

        asm volatile("s_waitcnt lgkmcnt(0)" ::: "memory");

        #pragma unroll
        for (int c = 0; c < 2; c++) {
            short8 pf[4], vf[4];
            #pragma unroll
            for (int mt = 0; mt < 4; mt++)
                pf[mt] = *reinterpret_cast<const short8*>(
                    cb + (mt * 16 + lrow) * 128 + (((4 * c + quad) ^ aofs) * 16));
            #pragma unroll
            for (int dt = 0; dt < 4; dt++)
                vf[dt] = *reinterpret_cast<const short8*>(
                    Vbase + (size_t)(dt * 16 + lrow) * SS + k0 + c * 32 + quad * 8);
            #pragma unroll
            for (int mt = 0; mt < 4; mt++)
                #pragma unroll
                for (int dt = 0; dt < 4; dt++)
                    oacc[mt][dt] = __builtin_amdgcn_mfma_f32_16x16x32_bf16(pf[mt], vf[dt], oacc[mt][dt], 0, 0, 0);
        }
    }

    #pragma unroll
    for (int nt = 0; nt < 4; nt++) {
        l[nt] += __shfl_xor(l[nt], 16, 64);
        l[nt] += __shfl_xor(l[nt], 32, 64);
    }
    float linv[4][4];
    #pragma unroll
    for (int mt = 0; mt < 4; mt++)
        #pragma unroll
        for (int r = 0; r < 4; r++)
            linv[mt][r] = 1.f / __shfl(l[mt], quad * 4 + r, 16);

    #pragma unroll
    for (int mt = 0; mt < 4; mt++) {
        #pragma unroll
        for (int r = 0; r < 4; r++) {
            int s_i = q0w + mt * 16 + quad * 4 + r;
            size_t row = (size_t)b * SS + s_i;
            #pragma unroll
            for (int dt = 0; dt < 4; dt++) {
                float x = oacc[mt][dt][r] * linv[mt][r];
                short hi = rne_bf16(x);
                short lo = rne_bf16(x - bf16f(hi));
                size_t idx = row * HH + (size_t)h * 64 + dt * 16 + lrow;
                Ah[idx] = hi;
                Al[idx] = lo;
            }
        }
    }
}

// ---------------- output projection GEMM, split-bf16 (3-term), LDS staged ----------------
__global__ void __launch_bounds__(256, 2)
k_gemm_wo(const short* __restrict__ Ahh, const short* __restrict__ All,
          const short* __restrict__ Bhh, const short* __restrict__ Bll,
          float* __restrict__ C)
{
    __shared__ short lAh[128 * 32];
    __shared__ short lAl[128 * 32];
    __shared__ short lBh[128 * 32];
    __shared__ short lBl[128 * 32];
    const int tid = threadIdx.x;
    const int lane = tid & 63;
    const int wave = tid >> 6;
    const int lrow = lane & 15;
    const int quad = lane >> 4;
    const int mblk = blockIdx.y * 128;
    const int nblk = blockIdx.x * 128;
    const int m0 = mblk + (wave >> 1) * 64;
    const int n0 = nblk + (wave & 1) * 64;
    const int mw = (wave >> 1) * 64;
    const int nw = (wave & 1) * 64;

    const int srow = wave * 32 + (lane >> 2);
    const int skc = (lane & 3) * 8;
    const short* gAh = Ahh + (size_t)(mblk + srow) * HH + skc;
    const short* gAl = All + (size_t)(mblk + srow) * HH + skc;
    const short* gBh = Bhh + (size_t)(nblk + srow) * HH + skc;
    const short* gBl = Bll + (size_t)(nblk + srow) * HH + skc;
    short* lAhw = &lAh[wave * 1024];
    short* lAlw = &lAl[wave * 1024];
    short* lBhw = &lBh[wave * 1024];
    short* lBlw = &lBl[wave * 1024];

    f32x4 acc[4][4];
    #pragma unroll
    for (int i = 0; i < 4; i++)
        #pragma unroll
        for (int j = 0; j < 4; j++) acc[i][j] = 0.f;

    #pragma unroll 1
    for (int k0 = 0; k0 < HH; k0 += 32) {
        __syncthreads();
        #pragma unroll
        for (int j = 0; j < 2; j++) {
            size_t go = (size_t)j * 16 * HH + k0;
            __builtin_amdgcn_global_load_lds((GLOBAL_AS)(gAh + go), (LDS_AS)(lAhw + j * 512), 16, 0, 0);
            __builtin_amdgcn_global_load_lds((GLOBAL_AS)(gAl + go), (LDS_AS)(lAlw + j * 512), 16, 0, 0);
            __builtin_amdgcn_global_load_lds((GLOBAL_AS)(gBh + go), (LDS_AS)(lBhw + j * 512), 16, 0, 0);
            __builtin_amdgcn_global_load_lds((GLOBAL_AS)(gBl + go), (LDS_AS)(lBlw + j * 512), 16, 0, 0);
        }
        __syncthreads();

        short8 ah[4], al[4], bh[4], bl[4];
        #pragma unroll
        for (int mt = 0; mt < 4; mt++) {
            int off = (mw + mt * 16 + lrow) * 32 + quad * 8;
            ah[mt] = *reinterpret_cast<const short8*>(&lAh[off]);
            al[mt] = *reinterpret_cast<const short8*>(&lAl[off]);
        }
        #pragma unroll
        for (int nt = 0; nt < 4; nt++) {
            int off = (nw + nt * 16 + lrow) * 32 + quad * 8;
            bh[nt] = *reinterpret_cast<const short8*>(&lBh[off]);
            bl[nt] = *reinterpret_cast<const short8*>(&lBl[off]);
        }
        #pragma unroll
        for (int mt = 0; mt < 4; mt++)
            #pragma unroll
            for (int nt = 0; nt < 4; nt++) {
                acc[mt][nt] = __builtin_amdgcn_mfma_f32_16x16x32_bf16(ah[mt], bh[nt], acc[mt][nt], 0, 0, 0);
                acc[mt][nt] = __builtin_amdgcn_mfma_f32_16x16x32_bf16(al[mt], bh[nt], acc[mt][nt], 0, 0, 0);
                acc[mt][nt] = __builtin_amdgcn_mfma_f32_16x16x32_bf16(ah[mt], bl[nt], acc[mt][nt], 0, 0, 0);
            }
    }

    #pragma unroll
    for (int mt = 0; mt < 4; mt++)
        #pragma unroll
        for (int r = 0; r < 4; r++) {
            int row = m0 + mt * 16 + quad * 4 + r;
            #pragma unroll
            for (int nt = 0; nt < 4; nt++) {
                int col = n0 + nt * 16 + lrow;
                C[(size_t)row * HH + col] = acc[mt][nt][r];
            }
        }
}

// ---------------- host launch ----------------
extern "C" void kernel_launch(void* const* d_in, const int* in_sizes, int n_in,
                              void* d_out, int out_size, void* d_ws, size_t ws_size,
                              hipStream_t stream) {
    const float* hidden = (const float*)d_in[0];
    const float* maskp  = (const float*)d_in[1];
    const float* cosT   = (const float*)d_in[2];
    const float* sinT   = (const float*)d_in[3];
    const float* Wq     = (const float*)d_in[4];
    const float* Wk     = (const float*)d_in[5];
    const float* Wv     = (const float*)d_in[6];
    const float* Wo     = (const float*)d_in[7];
    float* out = (float*)d_out;

    char* ws = (char*)d_ws;
    auto alloc = [&](size_t bytes) {
        char* p = ws;
        ws += (bytes + 255) & ~(size_t)255;
        return p;
    };
    const size_t XB = (size_t)MM * HH * sizeof(short);  // 16.78 MB
    const size_t WB = (size_t)HH * HH * sizeof(short);  //  8.39 MB
    short* Xh  = (short*)alloc(XB);
    short* Wqh = (short*)alloc(WB);
    short* Wkh = (short*)alloc(WB);
    short* Wvh = (short*)alloc(WB);
    short* Woh = (short*)alloc(WB);
    short* Wol = (short*)alloc(WB);
    short* Qr  = (short*)alloc(XB);
    short* Kr  = (short*)alloc(XB);
    short* Vt  = (short*)alloc(XB);
    short* Ah  = (short*)alloc(XB);
    short* Al  = (short*)alloc(XB);

    const int nX4 = MM * HH / 4;
    const int nW4 = HH * HH / 4;
    k_cvt<<<dim3(nX4 / 256), dim3(256), 0, stream>>>(hidden, Xh, nX4);
    k_cvt<<<dim3(nW4 / 256), dim3(256), 0, stream>>>(Wq, Wqh, nW4);
    k_cvt<<<dim3(nW4 / 256), dim3(256), 0, stream>>>(Wk, Wkh, nW4);
    k_cvt<<<dim3(nW4 / 256), dim3(256), 0, stream>>>(Wv, Wvh, nW4);
    k_cvt_split<<<dim3(nW4 / 256), dim3(256), 0, stream>>>(Wo, Woh, Wol, nW4);

    k_gemm_qkv<<<dim3(HH / 128, MM / 128), dim3(256), 0, stream>>>(
        Xh, Wqh, Wkh, Wvh, cosT, sinT, Qr, Kr, Vt);

    k_attn<<<dim3(SS / 256, NHH, NB), dim3(256), 0, stream>>>(
        Qr, Kr, Vt, maskp, Ah, Al);

    k_gemm_wo<<<dim3(HH / 128, MM / 128), dim3(256), 0, stream>>>(
        Ah, Al, Woh, Wol, out);
}

// Round 5
// 494.333 us; speedup vs baseline: 2.4367x; 1.0340x over previous
//
#include <hip/hip_runtime.h>
#include <stdint.h>
#include <math.h>

#define NB 2
#define SS 2048
#define HH 2048
#define NHH 32
#define HDD 64
#define MM (NB*SS)   // 4096

typedef __attribute__((ext_vector_type(8))) short short8;
typedef __attribute__((ext_vector_type(4))) short short4v;
typedef __attribute__((ext_vector_type(4))) float f32x4;

#define GLOBAL_AS const __attribute__((address_space(1))) void*
#define LDS_AS __attribute__((address_space(3))) void*

static __device__ __forceinline__ short rne_bf16(float x) {
    uint32_t u = __builtin_bit_cast(uint32_t, x);
    u += 0x7FFFu + ((u >> 16) & 1u);
    return (short)(u >> 16);
}
static __device__ __forceinline__ float bf16f(short h) {
    return __builtin_bit_cast(float, (uint32_t)((uint16_t)h) << 16);
}
static __device__ __forceinline__ uint32_t pack_bf16_rne(float a, float b) {
    uint32_t ua = __builtin_bit_cast(uint32_t, a);
    uint32_t ub = __builtin_bit_cast(uint32_t, b);
    ua += 0x7FFFu + ((ua >> 16) & 1u);
    ub += 0x7FFFu + ((ub >> 16) & 1u);
    return __builtin_amdgcn_perm(ub, ua, 0x07060302);
}
static __device__ __forceinline__ float fast_exp2(float x) {
    float r;
    asm("v_exp_f32 %0, %1" : "=v"(r) : "v"(x));
    return r;
}

// ---------------- convert fp32 -> bf16 (plain) ----------------
__global__ void __launch_bounds__(256)
k_cvt(const float* __restrict__ in, short* __restrict__ out, int n4) {
    int i = blockIdx.x * blockDim.x + threadIdx.x;
    if (i >= n4) return;
    float4 f = reinterpret_cast<const float4*>(in)[i];
    short4v o;
    o.x = rne_bf16(f.x); o.y = rne_bf16(f.y);
    o.z = rne_bf16(f.z); o.w = rne_bf16(f.w);
    reinterpret_cast<short4v*>(out)[i] = o;
}

// ---------------- convert fp32 -> bf16 hi + lo (split) ----------------
__global__ void __launch_bounds__(256)
k_cvt_split(const float* __restrict__ in, short* __restrict__ hi, short* __restrict__ lo, int n4) {
    int i = blockIdx.x * blockDim.x + threadIdx.x;
    if (i >= n4) return;
    float4 f = reinterpret_cast<const float4*>(in)[i];
    short4v h, l;
    h.x = rne_bf16(f.x); l.x = rne_bf16(f.x - bf16f(h.x));
    h.y = rne_bf16(f.y); l.y = rne_bf16(f.y - bf16f(h.y));
    h.z = rne_bf16(f.z); l.z = rne_bf16(f.z - bf16f(h.z));
    h.w = rne_bf16(f.w); l.w = rne_bf16(f.w - bf16f(h.w));
    reinterpret_cast<short4v*>(hi)[i] = h;
    reinterpret_cast<short4v*>(lo)[i] = l;
}

// ---------------- fused QKV projection GEMM + RoPE ----------------
// One block computes 128x128 tiles of Q, K, V simultaneously, sharing the
// A (X) tile: per K-step stage 4 tiles (A,Bq,Bk,Bv) and run 48 MFMAs.
__global__ void __launch_bounds__(256, 2)
k_gemm_qkv(const short* __restrict__ X,
           const short* __restrict__ Wqh, const short* __restrict__ Wkh, const short* __restrict__ Wvh,
           const float* __restrict__ cosT, const float* __restrict__ sinT,
           short* __restrict__ Qr, short* __restrict__ Kr, short* __restrict__ Vt)
{
    __shared__ short lA[128 * 32];
    __shared__ short lBq[128 * 32];
    __shared__ short lBk[128 * 32];
    __shared__ short lBv[128 * 32];
    const int tid = threadIdx.x;
    const int lane = tid & 63;
    const int wave = tid >> 6;
    const int lrow = lane & 15;
    const int quad = lane >> 4;
    const int mblk = blockIdx.y * 128;
    const int nblk = blockIdx.x * 128;
    const int m0 = mblk + (wave >> 1) * 64;
    const int n0 = nblk + (wave & 1) * 64;
    const int mw = (wave >> 1) * 64;
    const int nw = (wave & 1) * 64;

    // staging: wave w covers rows w*32 + j*16 + (lane>>2), k chunk (lane&3)*8
    const int srow = wave * 32 + (lane >> 2);
    const int skc = (lane & 3) * 8;
    const short* gA = X   + (size_t)(mblk + srow) * HH + skc;
    const short* gQ = Wqh + (size_t)(nblk + srow) * HH + skc;
    const short* gK = Wkh + (size_t)(nblk + srow) * HH + skc;
    const short* gV = Wvh + (size_t)(nblk + srow) * HH + skc;
    const int lofs = wave * 1024;

    f32x4 acc[3][4][4];
    #pragma unroll
    for (int z = 0; z < 3; z++)
        #pragma unroll
        for (int i = 0; i < 4; i++)
            #pragma unroll
            for (int j = 0; j < 4; j++) acc[z][i][j] = 0.f;

    #pragma unroll 1
    for (int k0 = 0; k0 < HH; k0 += 32) {
        __syncthreads();
        #pragma unroll
        for (int j = 0; j < 2; j++) {
            size_t go = (size_t)j * 16 * HH + k0;
            int lo = lofs + j * 512;
            __builtin_amdgcn_global_load_lds((GLOBAL_AS)(gA + go), (LDS_AS)(&lA[lo]),  16, 0, 0);
            __builtin_amdgcn_global_load_lds((GLOBAL_AS)(gQ + go), (LDS_AS)(&lBq[lo]), 16, 0, 0);
            __builtin_amdgcn_global_load_lds((GLOBAL_AS)(gK + go), (LDS_AS)(&lBk[lo]), 16, 0, 0);
            __builtin_amdgcn_global_load_lds((GLOBAL_AS)(gV + go), (LDS_AS)(&lBv[lo]), 16, 0, 0);
        }
        __syncthreads();

        short8 a[4];
        #pragma unroll
        for (int mt = 0; mt < 4; mt++)
            a[mt] = *reinterpret_cast<const short8*>(&lA[(mw + mt * 16 + lrow) * 32 + quad * 8]);

        const short* lBz[3] = { lBq, lBk, lBv };
        #pragma unroll
        for (int z = 0; z < 3; z++) {
            short8 b[4];
            #pragma unroll
            for (int nt = 0; nt < 4; nt++)
                b[nt] = *reinterpret_cast<const short8*>(&lBz[z][(nw + nt * 16 + lrow) * 32 + quad * 8]);
            #pragma unroll
            for (int mt = 0; mt < 4; mt++)
                #pragma unroll
                for (int nt = 0; nt < 4; nt++)
                    acc[z][mt][nt] = __builtin_amdgcn_mfma_f32_16x16x32_bf16(a[mt], b[nt], acc[z][mt][nt], 0, 0, 0);
        }
    }

    const float QSCL = 0.18033688011112042f;  // log2(e)/sqrt(HD)

    #pragma unroll
    for (int z = 0; z < 3; z++) {
        #pragma unroll
        for (int mt = 0; mt < 4; mt++) {
            #pragma unroll
            for (int r = 0; r < 4; r++) {
                int row = m0 + mt * 16 + quad * 4 + r;   // global m = b*S + s
                int b_i = row >> 11;
                int s_i = row & (SS - 1);
                #pragma unroll
                for (int nt = 0; nt < 4; nt++) {
                    int col = n0 + nt * 16 + lrow;       // global n = h*64 + d
                    int h_i = col >> 6;
                    int d_i = col & 63;
                    float v = acc[z][mt][nt][r];
                    if (z < 2) {
                        float pair = (nt & 2) ? acc[z][mt][nt - 2][r] : -acc[z][mt][nt + 2][r];
                        float c = cosT[s_i * HDD + d_i];
                        float sn = sinT[s_i * HDD + d_i];
                        v = v * c + pair * sn;
                        if (z == 0) v *= QSCL;
                        short* dst = (z == 0) ? Qr : Kr;
                        dst[(((size_t)b_i * NHH + h_i) * SS + s_i) * HDD + d_i] = rne_bf16(v);
                    } else {
                        Vt[(((size_t)b_i * NHH + h_i) * HDD + d_i) * SS + s_i] = rne_bf16(v);
                    }
                }
            }
        }
    }
}

// ---------------- flash attention: S^T MFMA + fixed-max softmax ----------------
// Grid: (bh=64, qblk=8). Linear block id = bh + 64*q -> XCD = bh%8, so all 8
// q-blocks of one (b,h) share one XCD's L2: K/V (512 KB/bh, 4 MB per XCD for
// its 8 bh) is HBM-fetched once per XCD instead of ~4.5x.
__global__ void __launch_bounds__(256, 2)
k_attn(const short* __restrict__ Qr, const short* __restrict__ Kr, const short* __restrict__ Vt,
       const float* __restrict__ mask,
       short* __restrict__ Ah, short* __restrict__ Al)
{
    __shared__ short plds[4][4096];   // per wave: 64 rows x 128 B (swizzled) = 8 KB
    const int lane = threadIdx.x & 63;
    const int wave = threadIdx.x >> 6;
    const int lrow = lane & 15;
    const int quad = lane >> 4;
    const int aofs = lrow & 7;
    const int b = blockIdx.x >> 5;
    const int h = blockIdx.x & 31;
    const int q0w = blockIdx.y * 256 + wave * 64;

    const size_t bh = (size_t)b * NHH + h;
    const short* Qbase = Qr + bh * SS * HDD;
    const short* Kbase = Kr + bh * SS * HDD;
    const short* Vbase = Vt + bh * (size_t)HDD * SS;
    const float* mrow = mask + b * SS;
    char* cb = (char*)&plds[wave][0];

    short8 qf[4][2];
    #pragma unroll
    for (int nt = 0; nt < 4; nt++)
        #pragma unroll
        for (int c = 0; c < 2; c++)
            qf[nt][c] = *reinterpret_cast<const short8*>(
                Qbase + (size_t)(q0w + nt * 16 + lrow) * HDD + c * 32 + quad * 8);

    f32x4 oacc[4][4];
    float l[4];
    #pragma unroll
    for (int i = 0; i < 4; i++) {
        l[i] = 0.f;
        #pragma unroll
        for (int j = 0; j < 4; j++) oacc[i][j] = 0.f;
    }

    const float L2E = 1.44269504f;

    #pragma unroll 1
    for (int k0 = 0; k0 < SS; k0 += 64) {
        short8 kf[4][2];
        #pragma unroll
        for (int kt = 0; kt < 4; kt++)
            #pragma unroll
            for (int c = 0; c < 2; c++)
                kf[kt][c] = *reinterpret_cast<const short8*>(
                    Kbase + (size_t)(k0 + kt * 16 + lrow) * HDD + c * 32 + quad * 8);

        f32x4 sacc[4][4];
        #pragma unroll
        for (int kt = 0; kt < 4; kt++)
            #pragma unroll
            for (int nt = 0; nt < 4; nt++) {
                f32x4 z4 = 0.f;
                z4 = __builtin_amdgcn_mfma_f32_16x16x32_bf16(kf[kt][0], qf[nt][0], z4, 0, 0, 0);
                sacc[kt][nt] = __builtin_amdgcn_mfma_f32_16x16x32_bf16(kf[kt][1], qf[nt][1], z4, 0, 0, 0);
            }

        asm volatile("s_waitcnt lgkmcnt(0)" ::: "memory");

        #pragma unroll
        for (int kt = 0; kt < 4; kt++) {
            float4 mk = *reinterpret_cast<const float4*>(mrow + k0 + kt * 16 + quad * 4);
            float m0v = mk.x * L2E, m1v = mk.y * L2E, m2v = mk.z * L2E, m3v = mk.w * L2E;
            #pragma unroll
            for (int nt = 0; nt < 4; nt++) {
                float p0 = fast_exp2(sacc[kt][nt][0] + m0v);
                float p1 = fast_exp2(sacc[kt][nt][1] + m1v);
                float p2 = fast_exp2(sacc[kt][nt][2] + m2v);
                float p3 = fast_exp2(sacc[kt][nt][3] + m3v);
                l[nt] += (p0 + p1) + (p2 + p3);
                uint2 w;
                w.x = pack_bf16_rne(p0, p1);
                w.y = pack_bf16_rne(p2, p3);
                *reinterpret_cast<uint2*>(
                    cb + (nt * 16 + lrow) * 128 +
                    (((2 * kt + (quad >> 1)) ^ aofs) * 16) + (quad & 1) * 8) = w;
            }
        }

        asm volatile("s_waitcnt lgkmcnt(0)" ::: "memory");

        #pragma unroll
        for (int c = 0; c < 2; c++) {
            short8 pf[4], vf[4];
            #pragma unroll
            for (int mt = 0; mt < 4; mt++)
                pf[mt] = *reinterpret_cast<const short8*>(
                    cb + (mt * 16 + lrow) * 128 + (((4 * c + quad) ^ aofs) * 16));
            #pragma unroll
            for (int dt = 0; dt < 4; dt++)
                vf[dt] = *reinterpret_cast<const short8*>(
                    Vbase + (size_t)(dt * 16 + lrow) * SS + k0 + c * 32 + quad * 8);
            #pragma unroll
            for (int mt = 0; mt < 4; mt++)
                #pragma unroll
                for (int dt = 0; dt < 4; dt++)
                    oacc[mt][dt] = __builtin_amdgcn_mfma_f32_16x16x32_bf16(pf[mt], vf[dt], oacc[mt][dt], 0, 0, 0);
        }
    }

    #pragma unroll
    for (int nt = 0; nt < 4; nt++) {
        l[nt] += __shfl_xor(l[nt], 16, 64);
        l[nt] += __shfl_xor(l[nt], 32, 64);
    }
    float linv[4][4];
    #pragma unroll
    for (int mt = 0; mt < 4; mt++)
        #pragma unroll
        for (int r = 0; r < 4; r++)
            linv[mt][r] = 1.f / __shfl(l[mt], quad * 4 + r, 16);

    #pragma unroll
    for (int mt = 0; mt < 4; mt++) {
        #pragma unroll
        for (int r = 0; r < 4; r++) {
            int s_i = q0w + mt * 16 + quad * 4 + r;
            size_t row = (size_t)b * SS + s_i;
            #pragma unroll
            for (int dt = 0; dt < 4; dt++) {
                float x = oacc[mt][dt][r] * linv[mt][r];
                short hi = rne_bf16(x);
                short lo = rne_bf16(x - bf16f(hi));
                size_t idx = row * HH + (size_t)h * 64 + dt * 16 + lrow;
                Ah[idx] = hi;
                Al[idx] = lo;
            }
        }
    }
}

// ---------------- output projection GEMM, split-bf16 (3-term), LDS staged ----------------
__global__ void __launch_bounds__(256, 2)
k_gemm_wo(const short* __restrict__ Ahh, const short* __restrict__ All,
          const short* __restrict__ Bhh, const short* __restrict__ Bll,
          float* __restrict__ C)
{
    __shared__ short lAh[128 * 32];
    __shared__ short lAl[128 * 32];
    __shared__ short lBh[128 * 32];
    __shared__ short lBl[128 * 32];
    const int tid = threadIdx.x;
    const int lane = tid & 63;
    const int wave = tid >> 6;
    const int lrow = lane & 15;
    const int quad = lane >> 4;
    const int mblk = blockIdx.y * 128;
    const int nblk = blockIdx.x * 128;
    const int m0 = mblk + (wave >> 1) * 64;
    const int n0 = nblk + (wave & 1) * 64;
    const int mw = (wave >> 1) * 64;
    const int nw = (wave & 1) * 64;

    const int srow = wave * 32 + (lane >> 2);
    const int skc = (lane & 3) * 8;
    const short* gAh = Ahh + (size_t)(mblk + srow) * HH + skc;
    const short* gAl = All + (size_t)(mblk + srow) * HH + skc;
    const short* gBh = Bhh + (size_t)(nblk + srow) * HH + skc;
    const short* gBl = Bll + (size_t)(nblk + srow) * HH + skc;
    short* lAhw = &lAh[wave * 1024];
    short* lAlw = &lAl[wave * 1024];
    short* lBhw = &lBh[wave * 1024];
    short* lBlw = &lBl[wave * 1024];

    f32x4 acc[4][4];
    #pragma unroll
    for (int i = 0; i < 4; i++)
        #pragma unroll
        for (int j = 0; j < 4; j++) acc[i][j] = 0.f;

    #pragma unroll 1
    for (int k0 = 0; k0 < HH; k0 += 32) {
        __syncthreads();
        #pragma unroll
        for (int j = 0; j < 2; j++) {
            size_t go = (size_t)j * 16 * HH + k0;
            __builtin_amdgcn_global_load_lds((GLOBAL_AS)(gAh + go), (LDS_AS)(lAhw + j * 512), 16, 0, 0);
            __builtin_amdgcn_global_load_lds((GLOBAL_AS)(gAl + go), (LDS_AS)(lAlw + j * 512), 16, 0, 0);
            __builtin_amdgcn_global_load_lds((GLOBAL_AS)(gBh + go), (LDS_AS)(lBhw + j * 512), 16, 0, 0);
            __builtin_amdgcn_global_load_lds((GLOBAL_AS)(gBl + go), (LDS_AS)(lBlw + j * 512), 16, 0, 0);
        }
        __syncthreads();

        short8 ah[4], al[4], bh[4], bl[4];
        #pragma unroll
        for (int mt = 0; mt < 4; mt++) {
            int off = (mw + mt * 16 + lrow) * 32 + quad * 8;
            ah[mt] = *reinterpret_cast<const short8*>(&lAh[off]);
            al[mt] = *reinterpret_cast<const short8*>(&lAl[off]);
        }
        #pragma unroll
        for (int nt = 0; nt < 4; nt++) {
            int off = (nw + nt * 16 + lrow) * 32 + quad * 8;
            bh[nt] = *reinterpret_cast<const short8*>(&lBh[off]);
            bl[nt] = *reinterpret_cast<const short8*>(&lBl[off]);
        }
        #pragma unroll
        for (int mt = 0; mt < 4; mt++)
            #pragma unroll
            for (int nt = 0; nt < 4; nt++) {
                acc[mt][nt] = __builtin_amdgcn_mfma_f32_16x16x32_bf16(ah[mt], bh[nt], acc[mt][nt], 0, 0, 0);
                acc[mt][nt] = __builtin_amdgcn_mfma_f32_16x16x32_bf16(al[mt], bh[nt], acc[mt][nt], 0, 0, 0);
                acc[mt][nt] = __builtin_amdgcn_mfma_f32_16x16x32_bf16(ah[mt], bl[nt], acc[mt][nt], 0, 0, 0);
            }
    }

    #pragma unroll
    for (int mt = 0; mt < 4; mt++)
        #pragma unroll
        for (int r = 0; r < 4; r++) {
            int row = m0 + mt * 16 + quad * 4 + r;
            #pragma unroll
            for (int nt = 0; nt < 4; nt++) {
                int col = n0 + nt * 16 + lrow;
                C[(size_t)row * HH + col] = acc[mt][nt][r];
            }
        }
}

// ---------------- host launch ----------------
extern "C" void kernel_launch(void* const* d_in, const int* in_sizes, int n_in,
                              void* d_out, int out_size, void* d_ws, size_t ws_size,
                              hipStream_t stream) {
    const float* hidden = (const float*)d_in[0];
    const float* maskp  = (const float*)d_in[1];
    const float* cosT   = (const float*)d_in[2];
    const float* sinT   = (const float*)d_in[3];
    const float* Wq     = (const float*)d_in[4];
    const float* Wk     = (const float*)d_in[5];
    const float* Wv     = (const float*)d_in[6];
    const float* Wo     = (const float*)d_in[7];
    float* out = (float*)d_out;

    char* ws = (char*)d_ws;
    auto alloc = [&](size_t bytes) {
        char* p = ws;
        ws += (bytes + 255) & ~(size_t)255;
        return p;
    };
    const size_t XB = (size_t)MM * HH * sizeof(short);  // 16.78 MB
    const size_t WB = (size_t)HH * HH * sizeof(short);  //  8.39 MB
    short* Xh  = (short*)alloc(XB);
    short* Wqh = (short*)alloc(WB);
    short* Wkh = (short*)alloc(WB);
    short* Wvh = (short*)alloc(WB);
    short* Woh = (short*)alloc(WB);
    short* Wol = (short*)alloc(WB);
    short* Qr  = (short*)alloc(XB);
    short* Kr  = (short*)alloc(XB);
    short* Vt  = (short*)alloc(XB);
    short* Ah  = (short*)alloc(XB);
    short* Al  = (short*)alloc(XB);

    const int nX4 = MM * HH / 4;
    const int nW4 = HH * HH / 4;
    k_cvt<<<dim3(nX4 / 256), dim3(256), 0, stream>>>(hidden, Xh, nX4);
    k_cvt<<<dim3(nW4 / 256), dim3(256), 0, stream>>>(Wq, Wqh, nW4);
    k_cvt<<<dim3(nW4 / 256), dim3(256), 0, stream>>>(Wk, Wkh, nW4);
    k_cvt<<<dim3(nW4 / 256), dim3(256), 0, stream>>>(Wv, Wvh, nW4);
    k_cvt_split<<<dim3(nW4 / 256), dim3(256), 0, stream>>>(Wo, Woh, Wol, nW4);

    k_gemm_qkv<<<dim3(HH / 128, MM / 128), dim3(256), 0, stream>>>(
        Xh, Wqh, Wkh, Wvh, cosT, sinT, Qr, Kr, Vt);

    k_attn<<<dim3(NB * NHH, SS / 256), dim3(256), 0, stream>>>(
        Qr, Kr, Vt, maskp, Ah, Al);

    k_gemm_wo<<<dim3(HH / 128, MM / 128), dim3(256), 0, stream>>>(
        Ah, Al, Woh, Wol, out);
}